// Round 4
// baseline (284.760 us; speedup 1.0000x reference)
//
#include <hip/hip_runtime.h>
#include <hip/hip_fp16.h>
#include <math.h>

// ---------------------------------------------------------------------------
// AttentionZP: swishmax attention, B=2, H=8, T=1024, A=64, C=256, Q=K=2048.
//
// Round 3 -> 4 (bugfix): flash_attn's c-split PV accumulates all 64 q in every
// wave, but online-swishmax state is per-q-owner-wave. Rescale events must
// therefore be applied by ALL waves to their acc columns. Each tile the owner
// wave publishes per-q sc = exp(m_old - m_new) (1.0 if none) to double-buffered
// sc_lds; after the P barrier every wave scales acc[*][qt] by sc before PV.
// ---------------------------------------------------------------------------

typedef _Float16 f16;
typedef _Float16 f16x4 __attribute__((ext_vector_type(4)));
typedef _Float16 f16x8 __attribute__((ext_vector_type(8)));
typedef short s16x4 __attribute__((ext_vector_type(4)));
typedef short bf16x8 __attribute__((ext_vector_type(8)));
typedef float f32x4 __attribute__((ext_vector_type(4)));

#define MFMA_F16(a, b, c) __builtin_amdgcn_mfma_f32_16x16x32_f16(a, b, c, 0, 0, 0)
#define MFMA_BF16(a, b, c) __builtin_amdgcn_mfma_f32_16x16x32_bf16(a, b, c, 0, 0, 0)

__device__ __forceinline__ void g2lds16(const void* g, void* l) {
  // async global->LDS, 16B/lane; LDS dest is wave-uniform base + lane*16
  __builtin_amdgcn_global_load_lds((__attribute__((address_space(1))) void*)g,
                                   (__attribute__((address_space(3))) void*)l, 16, 0, 0);
}

__device__ __forceinline__ short f32_bf16(float x) {
  union { float f; unsigned u; } v; v.f = x;
  unsigned r = v.u + 0x7FFFu + ((v.u >> 16) & 1u);  // RTN-even
  return (short)(r >> 16);
}
__device__ __forceinline__ float bf16_f32(short h) {
  union { unsigned u; float f; } v; v.u = ((unsigned)(unsigned short)h) << 16;
  return v.f;
}

// --------------------------- prep: elementwise split ------------------------
__global__ __launch_bounds__(256) void ew_split(const float* __restrict__ in,
                                                short* __restrict__ bhi,
                                                short* __restrict__ blo,
                                                f16* __restrict__ fo, int n4) {
  int i = blockIdx.x * 256 + threadIdx.x;
  int stride = gridDim.x * 256;
  for (; i < n4; i += stride) {
    f32x4 v = ((const f32x4*)in)[i];
    s16x4 h, l;
    f16x4 f;
#pragma unroll
    for (int j = 0; j < 4; j++) {
      short hj = f32_bf16(v[j]);
      h[j] = hj;
      l[j] = f32_bf16(v[j] - bf16_f32(hj));
      f[j] = (f16)v[j];
    }
    ((s16x4*)bhi)[i] = h;
    ((s16x4*)blo)[i] = l;
    if (fo) ((f16x4*)fo)[i] = f;
  }
}

// --------------------------- prep: transpose (+split) -----------------------
// in: [batch][R][C] f32 -> out: [batch][C][R]  (bf16 hi/lo and/or f16)
__global__ __launch_bounds__(256) void transpose_split(const float* __restrict__ in,
                                                       short* __restrict__ bhi,
                                                       short* __restrict__ blo,
                                                       f16* __restrict__ fo,
                                                       int R, int C) {
  __shared__ float t[64][65];
  int cb = blockIdx.x * 64, rb = blockIdx.y * 64;
  size_t batch = (size_t)blockIdx.z * R * C;
  int tid = threadIdx.x;
#pragma unroll
  for (int i = 0; i < 4; i++) {
    int r = (tid >> 4) + i * 16, c4 = (tid & 15) * 4;
    f32x4 v = *(const f32x4*)(in + batch + (size_t)(rb + r) * C + cb + c4);
    t[r][c4] = v[0]; t[r][c4 + 1] = v[1]; t[r][c4 + 2] = v[2]; t[r][c4 + 3] = v[3];
  }
  __syncthreads();
#pragma unroll
  for (int i = 0; i < 4; i++) {
    int c = (tid >> 4) + i * 16, r4 = (tid & 15) * 4;
    float v0 = t[r4][c], v1 = t[r4 + 1][c], v2 = t[r4 + 2][c], v3 = t[r4 + 3][c];
    size_t o = batch + (size_t)(cb + c) * R + rb + r4;
    if (bhi) {
      s16x4 h = {f32_bf16(v0), f32_bf16(v1), f32_bf16(v2), f32_bf16(v3)};
      *(s16x4*)(bhi + o) = h;
      s16x4 l = {f32_bf16(v0 - bf16_f32(h[0])), f32_bf16(v1 - bf16_f32(h[1])),
                 f32_bf16(v2 - bf16_f32(h[2])), f32_bf16(v3 - bf16_f32(h[3]))};
      *(s16x4*)(blo + o) = l;
    }
    if (fo) {
      f16x4 fv = {(f16)v0, (f16)v1, (f16)v2, (f16)v3};
      *(f16x4*)(fo + o) = fv;
    }
  }
}

// --------------------------- split-bf16 projection GEMM ----------------------
// M=4096(b,row) K=1024(t) N=512(h,a). Tile 64x128, 4 waves (2x2, 32x64 each).
// out: {q,k}_split[bh][row][ hi(64) | lo(64) ]  (bf16)
__global__ __launch_bounds__(256, 2) void proj_gemm(
    const short* __restrict__ qtok_hi, const short* __restrict__ qtok_lo,
    const short* __restrict__ ktok_hi, const short* __restrict__ ktok_lo,
    const short* __restrict__ wqT_hi, const short* __restrict__ wqT_lo,
    const short* __restrict__ wkT_hi, const short* __restrict__ wkT_lo,
    const float* __restrict__ bias, short* __restrict__ q_split,
    short* __restrict__ k_split) {
  const bool isQ = (blockIdx.z == 0);
  const short* Ahi = isQ ? qtok_hi : ktok_hi;
  const short* Alo = isQ ? qtok_lo : ktok_lo;
  const short* Bhi = isQ ? wqT_hi : wkT_hi;
  const short* Blo = isQ ? wqT_lo : wkT_lo;
  short* outp = isQ ? q_split : k_split;

  // regions (shorts): Ahi[0,2048) Alo[2048,4096) Bhi[4096,8192) Blo[8192,12288)
  __shared__ __attribute__((aligned(16))) short sm[2][12288];  // 48KB dbuf

  int tid = threadIdx.x, w = tid >> 6, lane = tid & 63, g = lane >> 4, li = lane & 15;
  int mb = blockIdx.y * 64, nb = blockIdx.x * 128;
  int wm = (w >> 1) * 32, wn = (w & 1) * 64;

  f32x4 acc[2][4] = {};

  auto STAGE = [&](int kb, int buf) {
    {
      int off = tid * 16;
      int row = off >> 6, ss = ((off >> 4) & 3) ^ ((row >> 1) & 3);
      size_t src = (size_t)(mb + row) * 1024 + kb + ss * 8;
      g2lds16(Ahi + src, (char*)&sm[buf][0] + w * 1024);
      g2lds16(Alo + src, (char*)&sm[buf][2048] + w * 1024);
    }
#pragma unroll
    for (int i = 0; i < 2; i++) {
      int off = i * 4096 + tid * 16;
      int row = off >> 6, ss = ((off >> 4) & 3) ^ ((row >> 1) & 3);
      size_t src = (size_t)(nb + row) * 1024 + kb + ss * 8;
      g2lds16(Bhi + src, (char*)&sm[buf][4096] + i * 4096 + w * 1024);
      g2lds16(Blo + src, (char*)&sm[buf][8192] + i * 4096 + w * 1024);
    }
  };

  STAGE(0, 0);
  __syncthreads();
  for (int kb = 0; kb < 1024; kb += 32) {
    int cur = (kb >> 5) & 1;
    if (kb + 32 < 1024) STAGE(kb + 32, cur ^ 1);
    bf16x8 af[2][2], bf[4][2];
#pragma unroll
    for (int f = 0; f < 2; f++) {
      int ra = wm + f * 16 + li, sa = g ^ ((ra >> 1) & 3);
      af[f][0] = *(const bf16x8*)&sm[cur][ra * 32 + sa * 8];
      af[f][1] = *(const bf16x8*)&sm[cur][2048 + ra * 32 + sa * 8];
    }
#pragma unroll
    for (int f = 0; f < 4; f++) {
      int rb = wn + f * 16 + li, sb = g ^ ((rb >> 1) & 3);
      bf[f][0] = *(const bf16x8*)&sm[cur][4096 + rb * 32 + sb * 8];
      bf[f][1] = *(const bf16x8*)&sm[cur][8192 + rb * 32 + sb * 8];
    }
#pragma unroll
    for (int mf = 0; mf < 2; mf++)
#pragma unroll
      for (int nf = 0; nf < 4; nf++) {
        acc[mf][nf] = MFMA_BF16(af[mf][0], bf[nf][0], acc[mf][nf]);
        acc[mf][nf] = MFMA_BF16(af[mf][0], bf[nf][1], acc[mf][nf]);
        acc[mf][nf] = MFMA_BF16(af[mf][1], bf[nf][0], acc[mf][nf]);
      }
    __syncthreads();
  }
#pragma unroll
  for (int mf = 0; mf < 2; mf++)
#pragma unroll
    for (int nf = 0; nf < 4; nf++)
#pragma unroll
      for (int r = 0; r < 4; r++) {
        int m = mb + wm + mf * 16 + 4 * g + r;
        int n = nb + wn + nf * 16 + li;
        float v = acc[mf][nf][r];
        if (isQ) v += bias[n];
        short hi = f32_bf16(v);
        short lo = f32_bf16(v - bf16_f32(hi));
        size_t base = ((size_t)((m >> 11) * 8 + (n >> 6)) * 2048 + (m & 2047)) * 128;
        outp[base + (n & 63)] = hi;
        outp[base + 64 + (n & 63)] = lo;
      }
}

// --------------------------- fp16 kv GEMM (writes kv k-blocked) -------------
// M=4096(key rows) K=1024(t) N=2048(h,c). Tile 64x128. 4 blocks/CU.
// out kvT[bh][kt=64][c=256][k=32] f16.
__global__ __launch_bounds__(256, 4) void kv_gemm(const f16* __restrict__ A,
                                                  const f16* __restrict__ Bm,
                                                  f16* __restrict__ kvT) {
  __shared__ __attribute__((aligned(16))) f16 sm[2][6144];  // A 2048 + B 4096, 24KB
  int tid = threadIdx.x, w = tid >> 6, lane = tid & 63, g = lane >> 4, li = lane & 15;
  int mb = blockIdx.y * 64, nb = blockIdx.x * 128;
  int wm = (w >> 1) * 32, wn = (w & 1) * 64;
  f32x4 acc[2][4] = {};

  auto STAGE = [&](int kb, int buf) {
    {
      int off = tid * 16;
      int row = off >> 6, ss = ((off >> 4) & 3) ^ ((row >> 1) & 3);
      g2lds16(A + (size_t)(mb + row) * 1024 + kb + ss * 8, (char*)&sm[buf][0] + w * 1024);
    }
#pragma unroll
    for (int i = 0; i < 2; i++) {
      int off = i * 4096 + tid * 16;
      int row = off >> 6, ss = ((off >> 4) & 3) ^ ((row >> 1) & 3);
      g2lds16(Bm + (size_t)(nb + row) * 1024 + kb + ss * 8,
              (char*)&sm[buf][2048] + i * 4096 + w * 1024);
    }
  };

  STAGE(0, 0);
  __syncthreads();
  for (int kb = 0; kb < 1024; kb += 32) {
    int cur = (kb >> 5) & 1;
    if (kb + 32 < 1024) STAGE(kb + 32, cur ^ 1);
    f16x8 af[2], bf[4];
#pragma unroll
    for (int f = 0; f < 2; f++) {
      int ra = wm + f * 16 + li, sa = g ^ ((ra >> 1) & 3);
      af[f] = *(const f16x8*)&sm[cur][ra * 32 + sa * 8];
    }
#pragma unroll
    for (int f = 0; f < 4; f++) {
      int rb = wn + f * 16 + li, sb = g ^ ((rb >> 1) & 3);
      bf[f] = *(const f16x8*)&sm[cur][2048 + rb * 32 + sb * 8];
    }
#pragma unroll
    for (int mf = 0; mf < 2; mf++)
#pragma unroll
      for (int nf = 0; nf < 4; nf++)
        acc[mf][nf] = MFMA_F16(af[mf], bf[nf], acc[mf][nf]);
    __syncthreads();
  }
#pragma unroll
  for (int mf = 0; mf < 2; mf++)
#pragma unroll
    for (int nf = 0; nf < 4; nf++) {
      int m = mb + wm + mf * 16 + 4 * g;  // 4 consecutive keys in regs 0..3
      int n = nb + wn + nf * 16 + li;     // (h<<8)|c
      f16x4 v = {(f16)acc[mf][nf][0], (f16)acc[mf][nf][1], (f16)acc[mf][nf][2],
                 (f16)acc[mf][nf][3]};
      int bh = (m >> 11) * 8 + (n >> 8);
      size_t o = (size_t)bh * 524288 + (size_t)((m & 2047) >> 5) * 8192 +
                 (size_t)(n & 255) * 32 + (m & 31);
      *(f16x4*)(kvT + o) = v;
    }
}

// --------------------------- flash swishmax attention ------------------------
// grid 512 (16 bh x 32 qb), 4 waves. QK^T: wave w computes S for q-slice w
// (16 q) with split-bf16 K-frags loaded global->regs (ping-pong prefetch).
// Online swishmax per lane (per q). P^T + per-q rescale factors exchanged via
// double-buffered LDS (one raw lgkmcnt+s_barrier per tile; no vmcnt drain in
// loop). PV: c-split, wave w owns c in [w*64,w*64+64) for ALL 64 q; kv loaded
// global->regs each tile from k-blocked kvT. All waves apply each q-owner's
// published rescale factor to their acc columns before PV.
__global__ __launch_bounds__(256, 2) void flash_attn(const short* __restrict__ q_split,
                                                     const short* __restrict__ k_split,
                                                     const f16* __restrict__ kvT,
                                                     f16* __restrict__ vs_c) {
  __shared__ __attribute__((aligned(16))) f16 p_lds[2][64 * 64];  // [buf][q][128B row], 16KB
  __shared__ float sc_lds[2][4][16];  // [buf][owner wave][q%16] rescale factors
  __shared__ float fix_lds[64];

  const int bid = blockIdx.x;
  const int bh = ((bid & 7) << 1) + ((bid >> 3) & 1);  // 2 bh per XCD for L2 locality
  const int qb = bid >> 4;
  const int tid = threadIdx.x;
  const int w = tid >> 6, lane = tid & 63, g = lane >> 4, li = lane & 15;

  // Q fragments (persist): B-operand, lane holds its q-row's a-slice
  const short* qrow = q_split + ((size_t)bh * 2048 + qb * 64 + w * 16 + li) * 128;
  bf16x8 qf[2][2];
#pragma unroll
  for (int ach = 0; ach < 2; ach++)
#pragma unroll
    for (int hl = 0; hl < 2; hl++)
      qf[ach][hl] = *(const bf16x8*)(qrow + hl * 64 + ach * 32 + g * 8);

  const short* kbase = k_split + (size_t)bh * 262144 + li * 128 + g * 8;
  const f16* kvbase = kvT + (size_t)bh * 524288 + (w * 64 + li) * 32 + g * 8;

  float m_cur = -INFINITY, m_true = -INFINITY, l_run = 0.f;
  f32x4 acc[4][4] = {};  // [ct][qt]
  bf16x8 ka[8], kb2[8];  // K frag ping-pong: [kc*4 + ach*2 + hi/lo]
  f16x8 kv[4];           // kv A-frags for this wave's c-quadrant

#define LOADK(dst, kt)                                                     \
  do {                                                                     \
    const short* _p = kbase + (kt) * 4096;                                 \
    _Pragma("unroll") for (int kc = 0; kc < 2; kc++)                       \
        _Pragma("unroll") for (int ach = 0; ach < 2; ach++) {              \
      dst[kc * 4 + ach * 2 + 0] = *(const bf16x8*)(_p + kc * 2048 + ach * 32);      \
      dst[kc * 4 + ach * 2 + 1] = *(const bf16x8*)(_p + kc * 2048 + 64 + ach * 32); \
    }                                                                      \
  } while (0)

#define LOADKV(kt)                                                         \
  do {                                                                     \
    const f16* _p = kvbase + (kt) * 8192;                                  \
    _Pragma("unroll") for (int ct = 0; ct < 4; ct++) kv[ct] =              \
        *(const f16x8*)(_p + ct * 512);                                    \
  } while (0)

  auto body = [&](bf16x8* kr, int buf) {
    // S^T[k, q]: 32 keys x this wave's 16 q (split-bf16, 3 terms)
    f32x4 s[2] = {};
    __builtin_amdgcn_s_setprio(1);
#pragma unroll
    for (int kc = 0; kc < 2; kc++)
#pragma unroll
      for (int ach = 0; ach < 2; ach++) {
        s[kc] = MFMA_BF16(kr[kc * 4 + ach * 2], qf[ach][0], s[kc]);
        s[kc] = MFMA_BF16(kr[kc * 4 + ach * 2], qf[ach][1], s[kc]);
        s[kc] = MFMA_BF16(kr[kc * 4 + ach * 2 + 1], qf[ach][0], s[kc]);
      }
    __builtin_amdgcn_s_setprio(0);

    // online swishmax; per-lane state is per-q (q = w*16+li after reductions)
    float tmax = fmaxf(fmaxf(fmaxf(s[0][0], s[0][1]), fmaxf(s[0][2], s[0][3])),
                       fmaxf(fmaxf(s[1][0], s[1][1]), fmaxf(s[1][2], s[1][3])));
    tmax = fmaxf(tmax, __shfl_xor(tmax, 16));
    tmax = fmaxf(tmax, __shfl_xor(tmax, 32));
    m_true = fmaxf(m_true, tmax);
    float sc = 1.0f;
    if (__any(tmax > m_cur + 4.0f)) {  // deferred rescale; P <= ~117*e^4 < f16 max
      float mn = fmaxf(m_cur, tmax);
      sc = __expf(m_cur - mn);  // per-q factor (1.0 where tmax <= m_cur)
      l_run *= sc;
      m_cur = mn;
    }
    // publish per-q rescale factor for acc owners (all waves hold acc for q)
    if (g == 0) sc_lds[buf][w][li] = sc;

    float ls = 0.f;
    float pv[8];
#pragma unroll
    for (int kc = 0; kc < 2; kc++)
#pragma unroll
      for (int r2 = 0; r2 < 4; r2++) {
        float sv = s[kc][r2];
        float e = sv * __expf(sv - m_cur);
        pv[kc * 4 + r2] = e;
        ls += fabsf(e);
      }
    ls += __shfl_xor(ls, 16);
    ls += __shfl_xor(ls, 32);
    l_run += ls;

    // write P^T[q][k] (f16) with q-row XOR swizzle ((q&7)<<4 on 128B rows)
#pragma unroll
    for (int kc = 0; kc < 2; kc++) {
      f16x4 p4 = {(f16)pv[kc * 4], (f16)pv[kc * 4 + 1], (f16)pv[kc * 4 + 2],
                  (f16)pv[kc * 4 + 3]};
      int wb = (((w * 16 + li) * 128 + kc * 32 + g * 8)) ^ ((li & 7) << 4);
      *(f16x4*)((char*)p_lds[buf] + wb) = p4;
    }
    // P + sc visible to all waves; raw barrier: does NOT drain vmcnt
    // (prefetches for tile t+1 stay in flight).
    asm volatile("s_waitcnt lgkmcnt(0)\n\ts_barrier" ::: "memory");

    // apply q-owners' rescale factors to our acc columns (rare after warmup)
#pragma unroll
    for (int qt = 0; qt < 4; qt++) {
      float scq = sc_lds[buf][qt][li];
      if (__any(scq != 1.0f)) {
#pragma unroll
        for (int ct = 0; ct < 4; ct++) acc[ct][qt] *= scq;
      }
    }

    // PV: acc[c-quadrant][all q] += kv[c][k] * P^T[k][q]
    __builtin_amdgcn_s_setprio(1);
#pragma unroll
    for (int qt = 0; qt < 4; qt++) {
      int rb = (((qt * 16 + li) * 128 + g * 16)) ^ ((li & 7) << 4);
      f16x8 pf = *(const f16x8*)((const char*)p_lds[buf] + rb);
#pragma unroll
      for (int ct = 0; ct < 4; ct++) acc[ct][qt] = MFMA_F16(kv[ct], pf, acc[ct][qt]);
    }
    __builtin_amdgcn_s_setprio(0);
  };

  LOADK(ka, 0);
#pragma unroll 1
  for (int kt = 0; kt < 64; kt += 2) {
    LOADKV(kt);            // kv(t): consumed in body-A's PV (vmcnt keeps K(t+1) in flight)
    LOADK(kb2, kt + 1);    // K(t+1) prefetch
    body(ka, 0);
    LOADKV(kt + 1);
    if (kt + 2 < 64) LOADK(ka, kt + 2);
    body(kb2, 1);
  }
#undef LOADK
#undef LOADKV

  // exact fixup to true max (swishmax NOT shift invariant: denom has +1);
  // fixup scalar lives in the q-owner wave -> broadcast via LDS.
  float sfix = __expf(m_cur - m_true);
  float invd = sfix / (l_run * sfix + 1.0f);
  if (g == 0) fix_lds[w * 16 + li] = invd;
  __syncthreads();
#pragma unroll
  for (int qt = 0; qt < 4; qt++) {
    float iv = fix_lds[qt * 16 + li];
    f16* orow = vs_c + ((size_t)(bh >> 3) * 2048 + qb * 64 + qt * 16 + li) * 2048 +
                (bh & 7) * 256 + w * 64 + g * 4;
#pragma unroll
    for (int ct = 0; ct < 4; ct++) {
      f16x4 v = {(f16)(acc[ct][qt][0] * iv), (f16)(acc[ct][qt][1] * iv),
                 (f16)(acc[ct][qt][2] * iv), (f16)(acc[ct][qt][3] * iv)};
      *(f16x4*)(orow + ct * 16) = v;
    }
  }
}

// --------------------------- fp16 final GEMM (head-sum in K) -----------------
// M=4096(b,q) K=2048(h,c) N=1024(t). Tile 64x128. out fp32.
__global__ __launch_bounds__(256, 2) void final_gemm(const f16* __restrict__ A,
                                                     const f16* __restrict__ Bm,
                                                     float* __restrict__ outp) {
  __shared__ __attribute__((aligned(16))) f16 sm[2][6144];  // 24KB dbuf
  int tid = threadIdx.x, w = tid >> 6, lane = tid & 63, g = lane >> 4, li = lane & 15;
  int mb = blockIdx.y * 64, nb = blockIdx.x * 128;
  int wm = (w >> 1) * 32, wn = (w & 1) * 64;
  f32x4 acc[2][4] = {};

  auto STAGE = [&](int kb, int buf) {
    {
      int off = tid * 16;
      int row = off >> 6, ss = ((off >> 4) & 3) ^ ((row >> 1) & 3);
      g2lds16(A + (size_t)(mb + row) * 2048 + kb + ss * 8, (char*)&sm[buf][0] + w * 1024);
    }
#pragma unroll
    for (int i = 0; i < 2; i++) {
      int off = i * 4096 + tid * 16;
      int row = off >> 6, ss = ((off >> 4) & 3) ^ ((row >> 1) & 3);
      g2lds16(Bm + (size_t)(nb + row) * 2048 + kb + ss * 8,
              (char*)&sm[buf][2048] + i * 4096 + w * 1024);
    }
  };

  STAGE(0, 0);
  __syncthreads();
  for (int kb = 0; kb < 2048; kb += 32) {
    int cur = (kb >> 5) & 1;
    if (kb + 32 < 2048) STAGE(kb + 32, cur ^ 1);
    f16x8 af[2], bf[4];
#pragma unroll
    for (int f = 0; f < 2; f++) {
      int ra = wm + f * 16 + li, sa = g ^ ((ra >> 1) & 3);
      af[f] = *(const f16x8*)&sm[cur][ra * 32 + sa * 8];
    }
#pragma unroll
    for (int f = 0; f < 4; f++) {
      int rb = wn + f * 16 + li, sb = g ^ ((rb >> 1) & 3);
      bf[f] = *(const f16x8*)&sm[cur][2048 + rb * 32 + sb * 8];
    }
#pragma unroll
    for (int mf = 0; mf < 2; mf++)
#pragma unroll
      for (int nf = 0; nf < 4; nf++)
        acc[mf][nf] = MFMA_F16(af[mf], bf[nf], acc[mf][nf]);
    __syncthreads();
  }
#pragma unroll
  for (int mf = 0; mf < 2; mf++)
#pragma unroll
    for (int nf = 0; nf < 4; nf++)
#pragma unroll
      for (int r = 0; r < 4; r++) {
        int m = mb + wm + mf * 16 + 4 * g + r;
        int n = nb + wn + nf * 16 + li;
        outp[(size_t)m * 1024 + n] = acc[mf][nf][r];
      }
}

// ---------------------------------------------------------------------------
extern "C" void kernel_launch(void* const* d_in, const int* in_sizes, int n_in,
                              void* d_out, int out_size, void* d_ws, size_t ws_size,
                              hipStream_t stream) {
  (void)in_sizes; (void)n_in; (void)out_size; (void)ws_size;
  const float* qtok = (const float*)d_in[0];  // [2,2048,1024]
  const float* ktok = (const float*)d_in[1];  // [2,2048,1024]
  const float* kdw = (const float*)d_in[2];   // [8,1024,64]
  const float* qdw = (const float*)d_in[3];   // [8,1024,64]
  const float* qdb = (const float*)d_in[4];   // [8,1,64]
  const float* vdw = (const float*)d_in[5];   // [8,1024,256]
  const float* vup = (const float*)d_in[6];   // [8,256,1024]

  char* ws = (char*)d_ws;
  size_t off = 0;
  auto take = [&](size_t n) { void* p = ws + off; off += (n + 255) & ~(size_t)255; return p; };

  short* qtok_hi = (short*)take(8u << 20);  // [4096][1024] bf16
  short* qtok_lo = (short*)take(8u << 20);
  short* ktok_hi = (short*)take(8u << 20);
  short* ktok_lo = (short*)take(8u << 20);
  f16* ktok_f = (f16*)take(8u << 20);       // [4096][1024] f16
  short* wqT_hi = (short*)take(1u << 20);   // [512][1024]
  short* wqT_lo = (short*)take(1u << 20);
  short* wkT_hi = (short*)take(1u << 20);
  short* wkT_lo = (short*)take(1u << 20);
  f16* vdT = (f16*)take(4u << 20);          // [2048][1024] f16 (Wv_down^T)
  f16* vuT = (f16*)take(4u << 20);          // [1024][2048] f16 (Wv_up^T)
  short* q_split = (short*)take(8u << 20);  // [16][2048][128] bf16 hi|lo
  short* k_split = (short*)take(8u << 20);
  // Aliased scratch (stream-ordered safe): {q,k}tok_{hi,lo} dead after proj_gemm.
  f16* kvT = (f16*)(void*)ktok_hi;   // 16MB: [16 bh][64 kt][256 c][32 k]
  f16* vs_c = (f16*)(void*)qtok_hi;  // 16MB: [2][2048][2048]

  ew_split<<<2048, 256, 0, stream>>>(qtok, qtok_hi, qtok_lo, (f16*)nullptr, 1048576);
  ew_split<<<2048, 256, 0, stream>>>(ktok, ktok_hi, ktok_lo, ktok_f, 1048576);
  transpose_split<<<dim3(1, 16, 8), 256, 0, stream>>>(qdw, wqT_hi, wqT_lo, nullptr, 1024, 64);
  transpose_split<<<dim3(1, 16, 8), 256, 0, stream>>>(kdw, wkT_hi, wkT_lo, nullptr, 1024, 64);
  transpose_split<<<dim3(4, 16, 8), 256, 0, stream>>>(vdw, nullptr, nullptr, vdT, 1024, 256);
  transpose_split<<<dim3(16, 32, 1), 256, 0, stream>>>(vup, nullptr, nullptr, vuT, 2048, 1024);

  proj_gemm<<<dim3(4, 64, 2), 256, 0, stream>>>(qtok_hi, qtok_lo, ktok_hi, ktok_lo,
                                                wqT_hi, wqT_lo, wkT_hi, wkT_lo, qdb,
                                                q_split, k_split);
  kv_gemm<<<dim3(16, 64), 256, 0, stream>>>(ktok_f, vdT, kvT);
  flash_attn<<<512, 256, 0, stream>>>(q_split, k_split, kvT, vs_c);
  final_gemm<<<dim3(8, 64), 256, 0, stream>>>(vs_c, vuT, (float*)d_out);
}

// Round 5
// 231.577 us; speedup vs baseline: 1.2297x; 1.2297x over previous
//
#include <hip/hip_runtime.h>
#include <hip/hip_fp16.h>
#include <math.h>

// ---------------------------------------------------------------------------
// AttentionZP: swishmax attention, B=2, H=8, T=1024, A=64, C=256, Q=K=2048.
//
// Round 4 -> 5: flash_attn hybrid. Round 4's c-split PV + per-q rescale
// publication (verified correct) is kept, but K and kv operands return to
// double-buffered LDS staging via global_load_lds (round-2 pattern): round 4's
// per-wave global K loads duplicated the K tile 4x into L2 and stalled on
// latency with only 2 waves/SIMD. With the c-split, per-wave LDS reads/iter
// drop from 27 (round 2) to 16 b128-class ops: K 8, kv 4, P 4 + 2 writes.
// kv staging now reads contiguous 16KB tiles (k-blocked kvT from kv_gemm).
// ---------------------------------------------------------------------------

typedef _Float16 f16;
typedef _Float16 f16x4 __attribute__((ext_vector_type(4)));
typedef _Float16 f16x8 __attribute__((ext_vector_type(8)));
typedef short s16x4 __attribute__((ext_vector_type(4)));
typedef short bf16x8 __attribute__((ext_vector_type(8)));
typedef float f32x4 __attribute__((ext_vector_type(4)));

#define MFMA_F16(a, b, c) __builtin_amdgcn_mfma_f32_16x16x32_f16(a, b, c, 0, 0, 0)
#define MFMA_BF16(a, b, c) __builtin_amdgcn_mfma_f32_16x16x32_bf16(a, b, c, 0, 0, 0)

__device__ __forceinline__ void g2lds16(const void* g, void* l) {
  // async global->LDS, 16B/lane; LDS dest is wave-uniform base + lane*16
  __builtin_amdgcn_global_load_lds((__attribute__((address_space(1))) void*)g,
                                   (__attribute__((address_space(3))) void*)l, 16, 0, 0);
}

__device__ __forceinline__ short f32_bf16(float x) {
  union { float f; unsigned u; } v; v.f = x;
  unsigned r = v.u + 0x7FFFu + ((v.u >> 16) & 1u);  // RTN-even
  return (short)(r >> 16);
}
__device__ __forceinline__ float bf16_f32(short h) {
  union { unsigned u; float f; } v; v.u = ((unsigned)(unsigned short)h) << 16;
  return v.f;
}

// --------------------------- prep: elementwise split ------------------------
__global__ __launch_bounds__(256) void ew_split(const float* __restrict__ in,
                                                short* __restrict__ bhi,
                                                short* __restrict__ blo,
                                                f16* __restrict__ fo, int n4) {
  int i = blockIdx.x * 256 + threadIdx.x;
  int stride = gridDim.x * 256;
  for (; i < n4; i += stride) {
    f32x4 v = ((const f32x4*)in)[i];
    s16x4 h, l;
    f16x4 f;
#pragma unroll
    for (int j = 0; j < 4; j++) {
      short hj = f32_bf16(v[j]);
      h[j] = hj;
      l[j] = f32_bf16(v[j] - bf16_f32(hj));
      f[j] = (f16)v[j];
    }
    ((s16x4*)bhi)[i] = h;
    ((s16x4*)blo)[i] = l;
    if (fo) ((f16x4*)fo)[i] = f;
  }
}

// --------------------------- prep: transpose (+split) -----------------------
// in: [batch][R][C] f32 -> out: [batch][C][R]  (bf16 hi/lo and/or f16)
__global__ __launch_bounds__(256) void transpose_split(const float* __restrict__ in,
                                                       short* __restrict__ bhi,
                                                       short* __restrict__ blo,
                                                       f16* __restrict__ fo,
                                                       int R, int C) {
  __shared__ float t[64][65];
  int cb = blockIdx.x * 64, rb = blockIdx.y * 64;
  size_t batch = (size_t)blockIdx.z * R * C;
  int tid = threadIdx.x;
#pragma unroll
  for (int i = 0; i < 4; i++) {
    int r = (tid >> 4) + i * 16, c4 = (tid & 15) * 4;
    f32x4 v = *(const f32x4*)(in + batch + (size_t)(rb + r) * C + cb + c4);
    t[r][c4] = v[0]; t[r][c4 + 1] = v[1]; t[r][c4 + 2] = v[2]; t[r][c4 + 3] = v[3];
  }
  __syncthreads();
#pragma unroll
  for (int i = 0; i < 4; i++) {
    int c = (tid >> 4) + i * 16, r4 = (tid & 15) * 4;
    float v0 = t[r4][c], v1 = t[r4 + 1][c], v2 = t[r4 + 2][c], v3 = t[r4 + 3][c];
    size_t o = batch + (size_t)(cb + c) * R + rb + r4;
    if (bhi) {
      s16x4 h = {f32_bf16(v0), f32_bf16(v1), f32_bf16(v2), f32_bf16(v3)};
      *(s16x4*)(bhi + o) = h;
      s16x4 l = {f32_bf16(v0 - bf16_f32(h[0])), f32_bf16(v1 - bf16_f32(h[1])),
                 f32_bf16(v2 - bf16_f32(h[2])), f32_bf16(v3 - bf16_f32(h[3]))};
      *(s16x4*)(blo + o) = l;
    }
    if (fo) {
      f16x4 fv = {(f16)v0, (f16)v1, (f16)v2, (f16)v3};
      *(f16x4*)(fo + o) = fv;
    }
  }
}

// --------------------------- split-bf16 projection GEMM ----------------------
// M=4096(b,row) K=1024(t) N=512(h,a). Tile 64x128, 4 waves (2x2, 32x64 each).
// out: {q,k}_split[bh][row][ hi(64) | lo(64) ]  (bf16)
__global__ __launch_bounds__(256, 2) void proj_gemm(
    const short* __restrict__ qtok_hi, const short* __restrict__ qtok_lo,
    const short* __restrict__ ktok_hi, const short* __restrict__ ktok_lo,
    const short* __restrict__ wqT_hi, const short* __restrict__ wqT_lo,
    const short* __restrict__ wkT_hi, const short* __restrict__ wkT_lo,
    const float* __restrict__ bias, short* __restrict__ q_split,
    short* __restrict__ k_split) {
  const bool isQ = (blockIdx.z == 0);
  const short* Ahi = isQ ? qtok_hi : ktok_hi;
  const short* Alo = isQ ? qtok_lo : ktok_lo;
  const short* Bhi = isQ ? wqT_hi : wkT_hi;
  const short* Blo = isQ ? wqT_lo : wkT_lo;
  short* outp = isQ ? q_split : k_split;

  // regions (shorts): Ahi[0,2048) Alo[2048,4096) Bhi[4096,8192) Blo[8192,12288)
  __shared__ __attribute__((aligned(16))) short sm[2][12288];  // 48KB dbuf

  int tid = threadIdx.x, w = tid >> 6, lane = tid & 63, g = lane >> 4, li = lane & 15;
  int mb = blockIdx.y * 64, nb = blockIdx.x * 128;
  int wm = (w >> 1) * 32, wn = (w & 1) * 64;

  f32x4 acc[2][4] = {};

  auto STAGE = [&](int kb, int buf) {
    {
      int off = tid * 16;
      int row = off >> 6, ss = ((off >> 4) & 3) ^ ((row >> 1) & 3);
      size_t src = (size_t)(mb + row) * 1024 + kb + ss * 8;
      g2lds16(Ahi + src, (char*)&sm[buf][0] + w * 1024);
      g2lds16(Alo + src, (char*)&sm[buf][2048] + w * 1024);
    }
#pragma unroll
    for (int i = 0; i < 2; i++) {
      int off = i * 4096 + tid * 16;
      int row = off >> 6, ss = ((off >> 4) & 3) ^ ((row >> 1) & 3);
      size_t src = (size_t)(nb + row) * 1024 + kb + ss * 8;
      g2lds16(Bhi + src, (char*)&sm[buf][4096] + i * 4096 + w * 1024);
      g2lds16(Blo + src, (char*)&sm[buf][8192] + i * 4096 + w * 1024);
    }
  };

  STAGE(0, 0);
  __syncthreads();
  for (int kb = 0; kb < 1024; kb += 32) {
    int cur = (kb >> 5) & 1;
    if (kb + 32 < 1024) STAGE(kb + 32, cur ^ 1);
    bf16x8 af[2][2], bf[4][2];
#pragma unroll
    for (int f = 0; f < 2; f++) {
      int ra = wm + f * 16 + li, sa = g ^ ((ra >> 1) & 3);
      af[f][0] = *(const bf16x8*)&sm[cur][ra * 32 + sa * 8];
      af[f][1] = *(const bf16x8*)&sm[cur][2048 + ra * 32 + sa * 8];
    }
#pragma unroll
    for (int f = 0; f < 4; f++) {
      int rb = wn + f * 16 + li, sb = g ^ ((rb >> 1) & 3);
      bf[f][0] = *(const bf16x8*)&sm[cur][4096 + rb * 32 + sb * 8];
      bf[f][1] = *(const bf16x8*)&sm[cur][8192 + rb * 32 + sb * 8];
    }
#pragma unroll
    for (int mf = 0; mf < 2; mf++)
#pragma unroll
      for (int nf = 0; nf < 4; nf++) {
        acc[mf][nf] = MFMA_BF16(af[mf][0], bf[nf][0], acc[mf][nf]);
        acc[mf][nf] = MFMA_BF16(af[mf][0], bf[nf][1], acc[mf][nf]);
        acc[mf][nf] = MFMA_BF16(af[mf][1], bf[nf][0], acc[mf][nf]);
      }
    __syncthreads();
  }
#pragma unroll
  for (int mf = 0; mf < 2; mf++)
#pragma unroll
    for (int nf = 0; nf < 4; nf++)
#pragma unroll
      for (int r = 0; r < 4; r++) {
        int m = mb + wm + mf * 16 + 4 * g + r;
        int n = nb + wn + nf * 16 + li;
        float v = acc[mf][nf][r];
        if (isQ) v += bias[n];
        short hi = f32_bf16(v);
        short lo = f32_bf16(v - bf16_f32(hi));
        size_t base = ((size_t)((m >> 11) * 8 + (n >> 6)) * 2048 + (m & 2047)) * 128;
        outp[base + (n & 63)] = hi;
        outp[base + 64 + (n & 63)] = lo;
      }
}

// --------------------------- fp16 kv GEMM (writes kv k-blocked) -------------
// M=4096(key rows) K=1024(t) N=2048(h,c). Tile 64x128. 4 blocks/CU.
// out kvT[bh][kt=64][c=256][k=32] f16.
__global__ __launch_bounds__(256, 4) void kv_gemm(const f16* __restrict__ A,
                                                  const f16* __restrict__ Bm,
                                                  f16* __restrict__ kvT) {
  __shared__ __attribute__((aligned(16))) f16 sm[2][6144];  // A 2048 + B 4096, 24KB
  int tid = threadIdx.x, w = tid >> 6, lane = tid & 63, g = lane >> 4, li = lane & 15;
  int mb = blockIdx.y * 64, nb = blockIdx.x * 128;
  int wm = (w >> 1) * 32, wn = (w & 1) * 64;
  f32x4 acc[2][4] = {};

  auto STAGE = [&](int kb, int buf) {
    {
      int off = tid * 16;
      int row = off >> 6, ss = ((off >> 4) & 3) ^ ((row >> 1) & 3);
      g2lds16(A + (size_t)(mb + row) * 1024 + kb + ss * 8, (char*)&sm[buf][0] + w * 1024);
    }
#pragma unroll
    for (int i = 0; i < 2; i++) {
      int off = i * 4096 + tid * 16;
      int row = off >> 6, ss = ((off >> 4) & 3) ^ ((row >> 1) & 3);
      g2lds16(Bm + (size_t)(nb + row) * 1024 + kb + ss * 8,
              (char*)&sm[buf][2048] + i * 4096 + w * 1024);
    }
  };

  STAGE(0, 0);
  __syncthreads();
  for (int kb = 0; kb < 1024; kb += 32) {
    int cur = (kb >> 5) & 1;
    if (kb + 32 < 1024) STAGE(kb + 32, cur ^ 1);
    f16x8 af[2], bf[4];
#pragma unroll
    for (int f = 0; f < 2; f++) {
      int ra = wm + f * 16 + li, sa = g ^ ((ra >> 1) & 3);
      af[f] = *(const f16x8*)&sm[cur][ra * 32 + sa * 8];
    }
#pragma unroll
    for (int f = 0; f < 4; f++) {
      int rb = wn + f * 16 + li, sb = g ^ ((rb >> 1) & 3);
      bf[f] = *(const f16x8*)&sm[cur][2048 + rb * 32 + sb * 8];
    }
#pragma unroll
    for (int mf = 0; mf < 2; mf++)
#pragma unroll
      for (int nf = 0; nf < 4; nf++)
        acc[mf][nf] = MFMA_F16(af[mf], bf[nf], acc[mf][nf]);
    __syncthreads();
  }
#pragma unroll
  for (int mf = 0; mf < 2; mf++)
#pragma unroll
    for (int nf = 0; nf < 4; nf++) {
      int m = mb + wm + mf * 16 + 4 * g;  // 4 consecutive keys in regs 0..3
      int n = nb + wn + nf * 16 + li;     // (h<<8)|c
      f16x4 v = {(f16)acc[mf][nf][0], (f16)acc[mf][nf][1], (f16)acc[mf][nf][2],
                 (f16)acc[mf][nf][3]};
      int bh = (m >> 11) * 8 + (n >> 8);
      size_t o = (size_t)bh * 524288 + (size_t)((m & 2047) >> 5) * 8192 +
                 (size_t)(n & 255) * 32 + (m & 31);
      *(f16x4*)(kvT + o) = v;
    }
}

// --------------------------- flash swishmax attention ------------------------
// grid 512 (16 bh x 32 qb), 4 waves. Per 32-key tile:
//  * K (8KB) and kv (16KB) staged to double-buffered LDS via global_load_lds
//    with pre-swizzled sources; STAGE(t+1) issued at top of iter t.
//  * QK^T: wave w computes S for q-slice w (16 q), split-bf16, K from LDS.
//  * online swishmax per lane (per q); per-q rescale factors published to
//    sc_lds; P^T written to swizzled p_lds. Raw lgkmcnt+s_barrier (no vmcnt
//    drain) makes P/sc visible.
//  * PV c-split: wave w owns c in [w*64,w*64+64) for ALL 64 q; kv + P from
//    LDS; all waves apply q-owners' rescale factors to acc before PV.
//  * __syncthreads at iter end drains vmcnt (staged bufs ready, reads done).
__global__ __launch_bounds__(256, 2) void flash_attn(const short* __restrict__ q_split,
                                                     const short* __restrict__ k_split,
                                                     const f16* __restrict__ kvT,
                                                     f16* __restrict__ vs_c) {
  __shared__ __attribute__((aligned(16))) short k_lds[2][4096];  // [32k][256B] 2x8KB
  __shared__ __attribute__((aligned(16))) f16 kv_lds[2][8192];   // [256c][64B] 2x16KB
  __shared__ __attribute__((aligned(16))) f16 p_lds[2][4096];    // [64q][128B] 2x8KB
  __shared__ float sc_lds[2][4][16];  // [buf][owner wave][q%16] rescale factors
  __shared__ float fix_lds[64];

  const int bid = blockIdx.x;
  const int bh = ((bid & 7) << 1) + ((bid >> 3) & 1);  // 2 bh per XCD for L2 locality
  const int qb = bid >> 4;
  const int tid = threadIdx.x;
  const int w = tid >> 6, lane = tid & 63, g = lane >> 4, li = lane & 15;

  // Q fragments (persist): B-operand, lane holds its q-row's a-slice
  const short* qrow = q_split + ((size_t)bh * 2048 + qb * 64 + w * 16 + li) * 128;
  bf16x8 qf[2][2];
#pragma unroll
  for (int ach = 0; ach < 2; ach++)
#pragma unroll
    for (int hl = 0; hl < 2; hl++)
      qf[ach][hl] = *(const bf16x8*)(qrow + hl * 64 + ach * 32 + g * 8);

  const short* kbase = k_split + (size_t)bh * 262144;
  const f16* kvbase = kvT + (size_t)bh * 524288;

  float m_cur = -INFINITY, m_true = -INFINITY, l_run = 0.f;
  f32x4 acc[4][4] = {};  // [ct][qt]

  auto STAGE = [&](int kt, int buf) {
    // K tile [32][256B rows, 16 slots of 16B], read-swz slot^(row&7)
#pragma unroll
    for (int i = 0; i < 2; i++) {
      int off = (w * 2 + i) * 1024 + lane * 16;
      int row = off >> 8;
      int ss = ((off >> 4) & 15) ^ (row & 7);
      g2lds16(kbase + kt * 4096 + row * 128 + ss * 8,
              (char*)k_lds[buf] + (w * 2 + i) * 1024);
    }
    // kv tile [256c][64B rows, 4 slots], read-swz slot^((c>>1)&3); source is
    // the contiguous 16KB k-blocked tile kvT[bh][kt][c][32k]
#pragma unroll
    for (int i = 0; i < 4; i++) {
      int off = (w * 4 + i) * 1024 + lane * 16;
      int c = off >> 6;
      int ss = ((off >> 4) & 3) ^ ((c >> 1) & 3);
      g2lds16(kvbase + kt * 8192 + c * 32 + ss * 8,
              (char*)kv_lds[buf] + (w * 4 + i) * 1024);
    }
  };

  STAGE(0, 0);
  __syncthreads();

#pragma unroll 1
  for (int kt = 0; kt < 64; kt++) {
    const int cur = kt & 1;
    if (kt < 63) STAGE(kt + 1, cur ^ 1);

    // S^T[k, q]: 32 keys x this wave's 16 q (split-bf16, 3 terms)
    f32x4 s[2] = {};
    __builtin_amdgcn_s_setprio(1);
#pragma unroll
    for (int kc = 0; kc < 2; kc++) {
      const int r = kc * 16 + li;
#pragma unroll
      for (int ach = 0; ach < 2; ach++) {
        int sh = (ach * 4 + g) ^ (r & 7);
        int sl = (8 + ach * 4 + g) ^ (r & 7);
        bf16x8 khi = *(const bf16x8*)((const char*)k_lds[cur] + r * 256 + sh * 16);
        bf16x8 klo = *(const bf16x8*)((const char*)k_lds[cur] + r * 256 + sl * 16);
        s[kc] = MFMA_BF16(khi, qf[ach][0], s[kc]);
        s[kc] = MFMA_BF16(khi, qf[ach][1], s[kc]);
        s[kc] = MFMA_BF16(klo, qf[ach][0], s[kc]);
      }
    }
    __builtin_amdgcn_s_setprio(0);

    // online swishmax; per-lane state is per-q (q = w*16+li after reductions)
    float tmax = fmaxf(fmaxf(fmaxf(s[0][0], s[0][1]), fmaxf(s[0][2], s[0][3])),
                       fmaxf(fmaxf(s[1][0], s[1][1]), fmaxf(s[1][2], s[1][3])));
    tmax = fmaxf(tmax, __shfl_xor(tmax, 16));
    tmax = fmaxf(tmax, __shfl_xor(tmax, 32));
    m_true = fmaxf(m_true, tmax);
    float sc = 1.0f;
    if (__any(tmax > m_cur + 4.0f)) {  // deferred rescale; P <= ~117*e^4 < f16 max
      float mn = fmaxf(m_cur, tmax);
      sc = __expf(m_cur - mn);  // per-q factor (1.0 where tmax <= m_cur)
      l_run *= sc;
      m_cur = mn;
    }
    // publish per-q rescale factor for acc owners (all waves hold acc for q)
    if (g == 0) sc_lds[cur][w][li] = sc;

    float ls = 0.f;
    float pv[8];
#pragma unroll
    for (int kc = 0; kc < 2; kc++)
#pragma unroll
      for (int r2 = 0; r2 < 4; r2++) {
        float sv = s[kc][r2];
        float e = sv * __expf(sv - m_cur);
        pv[kc * 4 + r2] = e;
        ls += fabsf(e);
      }
    ls += __shfl_xor(ls, 16);
    ls += __shfl_xor(ls, 32);
    l_run += ls;

    // write P^T[q][k] (f16) with q-row XOR swizzle ((q&7)<<4 on 128B rows)
#pragma unroll
    for (int kc = 0; kc < 2; kc++) {
      f16x4 p4 = {(f16)pv[kc * 4], (f16)pv[kc * 4 + 1], (f16)pv[kc * 4 + 2],
                  (f16)pv[kc * 4 + 3]};
      int wb = (((w * 16 + li) * 128 + kc * 32 + g * 8)) ^ ((li & 7) << 4);
      *(f16x4*)((char*)p_lds[cur] + wb) = p4;
    }
    // P + sc visible to all waves; raw barrier: does NOT drain vmcnt
    // (STAGE(t+1) loads stay in flight).
    asm volatile("s_waitcnt lgkmcnt(0)\n\ts_barrier" ::: "memory");

    // apply q-owners' rescale factors to our acc columns (rare after warmup)
#pragma unroll
    for (int qt = 0; qt < 4; qt++) {
      float scq = sc_lds[cur][qt][li];
      if (__any(scq != 1.0f)) {
#pragma unroll
        for (int ct = 0; ct < 4; ct++) acc[ct][qt] *= scq;
      }
    }

    // PV: acc[c-quadrant][all q] += kv[c][k] * P^T[k][q]  (kv + P from LDS)
    __builtin_amdgcn_s_setprio(1);
    f16x8 kvf[4];
#pragma unroll
    for (int ct = 0; ct < 4; ct++) {
      int c = w * 64 + ct * 16 + li;
      int ss = g ^ ((c >> 1) & 3);
      kvf[ct] = *(const f16x8*)((const char*)kv_lds[cur] + c * 64 + ss * 16);
    }
#pragma unroll
    for (int qt = 0; qt < 4; qt++) {
      int rb = (((qt * 16 + li) * 128 + g * 16)) ^ ((li & 7) << 4);
      f16x8 pf = *(const f16x8*)((const char*)p_lds[cur] + rb);
#pragma unroll
      for (int ct = 0; ct < 4; ct++) acc[ct][qt] = MFMA_F16(kvf[ct], pf, acc[ct][qt]);
    }
    __builtin_amdgcn_s_setprio(0);

    __syncthreads();  // drains vmcnt: staged bufs landed; all reads of cur done
  }

  // exact fixup to true max (swishmax NOT shift invariant: denom has +1);
  // fixup scalar lives in the q-owner wave -> broadcast via LDS.
  float sfix = __expf(m_cur - m_true);
  float invd = sfix / (l_run * sfix + 1.0f);
  if (g == 0) fix_lds[w * 16 + li] = invd;
  __syncthreads();
#pragma unroll
  for (int qt = 0; qt < 4; qt++) {
    float iv = fix_lds[qt * 16 + li];
    f16* orow = vs_c + ((size_t)(bh >> 3) * 2048 + qb * 64 + qt * 16 + li) * 2048 +
                (bh & 7) * 256 + w * 64 + g * 4;
#pragma unroll
    for (int ct = 0; ct < 4; ct++) {
      f16x4 v = {(f16)(acc[ct][qt][0] * iv), (f16)(acc[ct][qt][1] * iv),
                 (f16)(acc[ct][qt][2] * iv), (f16)(acc[ct][qt][3] * iv)};
      *(f16x4*)(orow + ct * 16) = v;
    }
  }
}

// --------------------------- fp16 final GEMM (head-sum in K) -----------------
// M=4096(b,q) K=2048(h,c) N=1024(t). Tile 64x128. out fp32.
__global__ __launch_bounds__(256, 2) void final_gemm(const f16* __restrict__ A,
                                                     const f16* __restrict__ Bm,
                                                     float* __restrict__ outp) {
  __shared__ __attribute__((aligned(16))) f16 sm[2][6144];  // 24KB dbuf
  int tid = threadIdx.x, w = tid >> 6, lane = tid & 63, g = lane >> 4, li = lane & 15;
  int mb = blockIdx.y * 64, nb = blockIdx.x * 128;
  int wm = (w >> 1) * 32, wn = (w & 1) * 64;
  f32x4 acc[2][4] = {};

  auto STAGE = [&](int kb, int buf) {
    {
      int off = tid * 16;
      int row = off >> 6, ss = ((off >> 4) & 3) ^ ((row >> 1) & 3);
      g2lds16(A + (size_t)(mb + row) * 2048 + kb + ss * 8, (char*)&sm[buf][0] + w * 1024);
    }
#pragma unroll
    for (int i = 0; i < 2; i++) {
      int off = i * 4096 + tid * 16;
      int row = off >> 6, ss = ((off >> 4) & 3) ^ ((row >> 1) & 3);
      g2lds16(Bm + (size_t)(nb + row) * 2048 + kb + ss * 8,
              (char*)&sm[buf][2048] + i * 4096 + w * 1024);
    }
  };

  STAGE(0, 0);
  __syncthreads();
  for (int kb = 0; kb < 2048; kb += 32) {
    int cur = (kb >> 5) & 1;
    if (kb + 32 < 2048) STAGE(kb + 32, cur ^ 1);
    f16x8 af[2], bf[4];
#pragma unroll
    for (int f = 0; f < 2; f++) {
      int ra = wm + f * 16 + li, sa = g ^ ((ra >> 1) & 3);
      af[f] = *(const f16x8*)&sm[cur][ra * 32 + sa * 8];
    }
#pragma unroll
    for (int f = 0; f < 4; f++) {
      int rb = wn + f * 16 + li, sb = g ^ ((rb >> 1) & 3);
      bf[f] = *(const f16x8*)&sm[cur][2048 + rb * 32 + sb * 8];
    }
#pragma unroll
    for (int mf = 0; mf < 2; mf++)
#pragma unroll
      for (int nf = 0; nf < 4; nf++)
        acc[mf][nf] = MFMA_F16(af[mf], bf[nf], acc[mf][nf]);
    __syncthreads();
  }
#pragma unroll
  for (int mf = 0; mf < 2; mf++)
#pragma unroll
    for (int nf = 0; nf < 4; nf++)
#pragma unroll
      for (int r = 0; r < 4; r++) {
        int m = mb + wm + mf * 16 + 4 * g + r;
        int n = nb + wn + nf * 16 + li;
        outp[(size_t)m * 1024 + n] = acc[mf][nf][r];
      }
}

// ---------------------------------------------------------------------------
extern "C" void kernel_launch(void* const* d_in, const int* in_sizes, int n_in,
                              void* d_out, int out_size, void* d_ws, size_t ws_size,
                              hipStream_t stream) {
  (void)in_sizes; (void)n_in; (void)out_size; (void)ws_size;
  const float* qtok = (const float*)d_in[0];  // [2,2048,1024]
  const float* ktok = (const float*)d_in[1];  // [2,2048,1024]
  const float* kdw = (const float*)d_in[2];   // [8,1024,64]
  const float* qdw = (const float*)d_in[3];   // [8,1024,64]
  const float* qdb = (const float*)d_in[4];   // [8,1,64]
  const float* vdw = (const float*)d_in[5];   // [8,1024,256]
  const float* vup = (const float*)d_in[6];   // [8,256,1024]

  char* ws = (char*)d_ws;
  size_t off = 0;
  auto take = [&](size_t n) { void* p = ws + off; off += (n + 255) & ~(size_t)255; return p; };

  short* qtok_hi = (short*)take(8u << 20);  // [4096][1024] bf16
  short* qtok_lo = (short*)take(8u << 20);
  short* ktok_hi = (short*)take(8u << 20);
  short* ktok_lo = (short*)take(8u << 20);
  f16* ktok_f = (f16*)take(8u << 20);       // [4096][1024] f16
  short* wqT_hi = (short*)take(1u << 20);   // [512][1024]
  short* wqT_lo = (short*)take(1u << 20);
  short* wkT_hi = (short*)take(1u << 20);
  short* wkT_lo = (short*)take(1u << 20);
  f16* vdT = (f16*)take(4u << 20);          // [2048][1024] f16 (Wv_down^T)
  f16* vuT = (f16*)take(4u << 20);          // [1024][2048] f16 (Wv_up^T)
  short* q_split = (short*)take(8u << 20);  // [16][2048][128] bf16 hi|lo
  short* k_split = (short*)take(8u << 20);
  // Aliased scratch (stream-ordered safe): {q,k}tok_{hi,lo} dead after proj_gemm.
  f16* kvT = (f16*)(void*)ktok_hi;   // 16MB: [16 bh][64 kt][256 c][32 k]
  f16* vs_c = (f16*)(void*)qtok_hi;  // 16MB: [2][2048][2048]

  ew_split<<<2048, 256, 0, stream>>>(qtok, qtok_hi, qtok_lo, (f16*)nullptr, 1048576);
  ew_split<<<2048, 256, 0, stream>>>(ktok, ktok_hi, ktok_lo, ktok_f, 1048576);
  transpose_split<<<dim3(1, 16, 8), 256, 0, stream>>>(qdw, wqT_hi, wqT_lo, nullptr, 1024, 64);
  transpose_split<<<dim3(1, 16, 8), 256, 0, stream>>>(kdw, wkT_hi, wkT_lo, nullptr, 1024, 64);
  transpose_split<<<dim3(4, 16, 8), 256, 0, stream>>>(vdw, nullptr, nullptr, vdT, 1024, 256);
  transpose_split<<<dim3(16, 32, 1), 256, 0, stream>>>(vup, nullptr, nullptr, vuT, 2048, 1024);

  proj_gemm<<<dim3(4, 64, 2), 256, 0, stream>>>(qtok_hi, qtok_lo, ktok_hi, ktok_lo,
                                                wqT_hi, wqT_lo, wkT_hi, wkT_lo, qdb,
                                                q_split, k_split);
  kv_gemm<<<dim3(16, 64), 256, 0, stream>>>(ktok_f, vdT, kvT);
  flash_attn<<<512, 256, 0, stream>>>(q_split, k_split, kvT, vs_c);
  final_gemm<<<dim3(8, 64), 256, 0, stream>>>(vs_c, vuT, (float*)d_out);
}

// Round 6
// 227.981 us; speedup vs baseline: 1.2491x; 1.0158x over previous
//
#include <hip/hip_runtime.h>
#include <hip/hip_fp16.h>
#include <math.h>

// ---------------------------------------------------------------------------
// AttentionZP: swishmax attention, B=2, H=8, T=1024, A=64, C=256, Q=K=2048.
//
// Round 5 -> 6: flash_attn skewed pipeline, ONE barrier per tile. PV(t) only
// needs P(t)/sc(t) published the PREVIOUS iteration (double-buffered), so the
// loop computes QK+softmax for tile t+1, publishes into parity t+1, then runs
// PV(t) from parity t — softmax(t+1) VALU and PV(t) MFMA are independent and
// can interleave. The single __syncthreads per iter makes P/sc visible AND
// drains the global_load_lds staging issued one iteration earlier.
// ---------------------------------------------------------------------------

typedef _Float16 f16;
typedef _Float16 f16x4 __attribute__((ext_vector_type(4)));
typedef _Float16 f16x8 __attribute__((ext_vector_type(8)));
typedef short s16x4 __attribute__((ext_vector_type(4)));
typedef short bf16x8 __attribute__((ext_vector_type(8)));
typedef float f32x4 __attribute__((ext_vector_type(4)));

#define MFMA_F16(a, b, c) __builtin_amdgcn_mfma_f32_16x16x32_f16(a, b, c, 0, 0, 0)
#define MFMA_BF16(a, b, c) __builtin_amdgcn_mfma_f32_16x16x32_bf16(a, b, c, 0, 0, 0)

__device__ __forceinline__ void g2lds16(const void* g, void* l) {
  // async global->LDS, 16B/lane; LDS dest is wave-uniform base + lane*16
  __builtin_amdgcn_global_load_lds((__attribute__((address_space(1))) void*)g,
                                   (__attribute__((address_space(3))) void*)l, 16, 0, 0);
}

__device__ __forceinline__ short f32_bf16(float x) {
  union { float f; unsigned u; } v; v.f = x;
  unsigned r = v.u + 0x7FFFu + ((v.u >> 16) & 1u);  // RTN-even
  return (short)(r >> 16);
}
__device__ __forceinline__ float bf16_f32(short h) {
  union { unsigned u; float f; } v; v.u = ((unsigned)(unsigned short)h) << 16;
  return v.f;
}

// --------------------------- prep: elementwise split ------------------------
__global__ __launch_bounds__(256) void ew_split(const float* __restrict__ in,
                                                short* __restrict__ bhi,
                                                short* __restrict__ blo,
                                                f16* __restrict__ fo, int n4) {
  int i = blockIdx.x * 256 + threadIdx.x;
  int stride = gridDim.x * 256;
  for (; i < n4; i += stride) {
    f32x4 v = ((const f32x4*)in)[i];
    s16x4 h, l;
    f16x4 f;
#pragma unroll
    for (int j = 0; j < 4; j++) {
      short hj = f32_bf16(v[j]);
      h[j] = hj;
      l[j] = f32_bf16(v[j] - bf16_f32(hj));
      f[j] = (f16)v[j];
    }
    ((s16x4*)bhi)[i] = h;
    ((s16x4*)blo)[i] = l;
    if (fo) ((f16x4*)fo)[i] = f;
  }
}

// --------------------------- prep: transpose (+split) -----------------------
// in: [batch][R][C] f32 -> out: [batch][C][R]  (bf16 hi/lo and/or f16)
__global__ __launch_bounds__(256) void transpose_split(const float* __restrict__ in,
                                                       short* __restrict__ bhi,
                                                       short* __restrict__ blo,
                                                       f16* __restrict__ fo,
                                                       int R, int C) {
  __shared__ float t[64][65];
  int cb = blockIdx.x * 64, rb = blockIdx.y * 64;
  size_t batch = (size_t)blockIdx.z * R * C;
  int tid = threadIdx.x;
#pragma unroll
  for (int i = 0; i < 4; i++) {
    int r = (tid >> 4) + i * 16, c4 = (tid & 15) * 4;
    f32x4 v = *(const f32x4*)(in + batch + (size_t)(rb + r) * C + cb + c4);
    t[r][c4] = v[0]; t[r][c4 + 1] = v[1]; t[r][c4 + 2] = v[2]; t[r][c4 + 3] = v[3];
  }
  __syncthreads();
#pragma unroll
  for (int i = 0; i < 4; i++) {
    int c = (tid >> 4) + i * 16, r4 = (tid & 15) * 4;
    float v0 = t[r4][c], v1 = t[r4 + 1][c], v2 = t[r4 + 2][c], v3 = t[r4 + 3][c];
    size_t o = batch + (size_t)(cb + c) * R + rb + r4;
    if (bhi) {
      s16x4 h = {f32_bf16(v0), f32_bf16(v1), f32_bf16(v2), f32_bf16(v3)};
      *(s16x4*)(bhi + o) = h;
      s16x4 l = {f32_bf16(v0 - bf16_f32(h[0])), f32_bf16(v1 - bf16_f32(h[1])),
                 f32_bf16(v2 - bf16_f32(h[2])), f32_bf16(v3 - bf16_f32(h[3]))};
      *(s16x4*)(blo + o) = l;
    }
    if (fo) {
      f16x4 fv = {(f16)v0, (f16)v1, (f16)v2, (f16)v3};
      *(f16x4*)(fo + o) = fv;
    }
  }
}

// --------------------------- split-bf16 projection GEMM ----------------------
// M=4096(b,row) K=1024(t) N=512(h,a). Tile 64x128, 4 waves (2x2, 32x64 each).
// out: {q,k}_split[bh][row][ hi(64) | lo(64) ]  (bf16)
__global__ __launch_bounds__(256, 2) void proj_gemm(
    const short* __restrict__ qtok_hi, const short* __restrict__ qtok_lo,
    const short* __restrict__ ktok_hi, const short* __restrict__ ktok_lo,
    const short* __restrict__ wqT_hi, const short* __restrict__ wqT_lo,
    const short* __restrict__ wkT_hi, const short* __restrict__ wkT_lo,
    const float* __restrict__ bias, short* __restrict__ q_split,
    short* __restrict__ k_split) {
  const bool isQ = (blockIdx.z == 0);
  const short* Ahi = isQ ? qtok_hi : ktok_hi;
  const short* Alo = isQ ? qtok_lo : ktok_lo;
  const short* Bhi = isQ ? wqT_hi : wkT_hi;
  const short* Blo = isQ ? wqT_lo : wkT_lo;
  short* outp = isQ ? q_split : k_split;

  // regions (shorts): Ahi[0,2048) Alo[2048,4096) Bhi[4096,8192) Blo[8192,12288)
  __shared__ __attribute__((aligned(16))) short sm[2][12288];  // 48KB dbuf

  int tid = threadIdx.x, w = tid >> 6, lane = tid & 63, g = lane >> 4, li = lane & 15;
  int mb = blockIdx.y * 64, nb = blockIdx.x * 128;
  int wm = (w >> 1) * 32, wn = (w & 1) * 64;

  f32x4 acc[2][4] = {};

  auto STAGE = [&](int kb, int buf) {
    {
      int off = tid * 16;
      int row = off >> 6, ss = ((off >> 4) & 3) ^ ((row >> 1) & 3);
      size_t src = (size_t)(mb + row) * 1024 + kb + ss * 8;
      g2lds16(Ahi + src, (char*)&sm[buf][0] + w * 1024);
      g2lds16(Alo + src, (char*)&sm[buf][2048] + w * 1024);
    }
#pragma unroll
    for (int i = 0; i < 2; i++) {
      int off = i * 4096 + tid * 16;
      int row = off >> 6, ss = ((off >> 4) & 3) ^ ((row >> 1) & 3);
      size_t src = (size_t)(nb + row) * 1024 + kb + ss * 8;
      g2lds16(Bhi + src, (char*)&sm[buf][4096] + i * 4096 + w * 1024);
      g2lds16(Blo + src, (char*)&sm[buf][8192] + i * 4096 + w * 1024);
    }
  };

  STAGE(0, 0);
  __syncthreads();
  for (int kb = 0; kb < 1024; kb += 32) {
    int cur = (kb >> 5) & 1;
    if (kb + 32 < 1024) STAGE(kb + 32, cur ^ 1);
    bf16x8 af[2][2], bf[4][2];
#pragma unroll
    for (int f = 0; f < 2; f++) {
      int ra = wm + f * 16 + li, sa = g ^ ((ra >> 1) & 3);
      af[f][0] = *(const bf16x8*)&sm[cur][ra * 32 + sa * 8];
      af[f][1] = *(const bf16x8*)&sm[cur][2048 + ra * 32 + sa * 8];
    }
#pragma unroll
    for (int f = 0; f < 4; f++) {
      int rb = wn + f * 16 + li, sb = g ^ ((rb >> 1) & 3);
      bf[f][0] = *(const bf16x8*)&sm[cur][4096 + rb * 32 + sb * 8];
      bf[f][1] = *(const bf16x8*)&sm[cur][8192 + rb * 32 + sb * 8];
    }
#pragma unroll
    for (int mf = 0; mf < 2; mf++)
#pragma unroll
      for (int nf = 0; nf < 4; nf++) {
        acc[mf][nf] = MFMA_BF16(af[mf][0], bf[nf][0], acc[mf][nf]);
        acc[mf][nf] = MFMA_BF16(af[mf][0], bf[nf][1], acc[mf][nf]);
        acc[mf][nf] = MFMA_BF16(af[mf][1], bf[nf][0], acc[mf][nf]);
      }
    __syncthreads();
  }
#pragma unroll
  for (int mf = 0; mf < 2; mf++)
#pragma unroll
    for (int nf = 0; nf < 4; nf++)
#pragma unroll
      for (int r = 0; r < 4; r++) {
        int m = mb + wm + mf * 16 + 4 * g + r;
        int n = nb + wn + nf * 16 + li;
        float v = acc[mf][nf][r];
        if (isQ) v += bias[n];
        short hi = f32_bf16(v);
        short lo = f32_bf16(v - bf16_f32(hi));
        size_t base = ((size_t)((m >> 11) * 8 + (n >> 6)) * 2048 + (m & 2047)) * 128;
        outp[base + (n & 63)] = hi;
        outp[base + 64 + (n & 63)] = lo;
      }
}

// --------------------------- fp16 kv GEMM (writes kv k-blocked) -------------
// M=4096(key rows) K=1024(t) N=2048(h,c). Tile 64x128. 4 blocks/CU.
// out kvT[bh][kt=64][c=256][k=32] f16.
__global__ __launch_bounds__(256, 4) void kv_gemm(const f16* __restrict__ A,
                                                  const f16* __restrict__ Bm,
                                                  f16* __restrict__ kvT) {
  __shared__ __attribute__((aligned(16))) f16 sm[2][6144];  // A 2048 + B 4096, 24KB
  int tid = threadIdx.x, w = tid >> 6, lane = tid & 63, g = lane >> 4, li = lane & 15;
  int mb = blockIdx.y * 64, nb = blockIdx.x * 128;
  int wm = (w >> 1) * 32, wn = (w & 1) * 64;
  f32x4 acc[2][4] = {};

  auto STAGE = [&](int kb, int buf) {
    {
      int off = tid * 16;
      int row = off >> 6, ss = ((off >> 4) & 3) ^ ((row >> 1) & 3);
      g2lds16(A + (size_t)(mb + row) * 1024 + kb + ss * 8, (char*)&sm[buf][0] + w * 1024);
    }
#pragma unroll
    for (int i = 0; i < 2; i++) {
      int off = i * 4096 + tid * 16;
      int row = off >> 6, ss = ((off >> 4) & 3) ^ ((row >> 1) & 3);
      g2lds16(Bm + (size_t)(nb + row) * 1024 + kb + ss * 8,
              (char*)&sm[buf][2048] + i * 4096 + w * 1024);
    }
  };

  STAGE(0, 0);
  __syncthreads();
  for (int kb = 0; kb < 1024; kb += 32) {
    int cur = (kb >> 5) & 1;
    if (kb + 32 < 1024) STAGE(kb + 32, cur ^ 1);
    f16x8 af[2], bf[4];
#pragma unroll
    for (int f = 0; f < 2; f++) {
      int ra = wm + f * 16 + li, sa = g ^ ((ra >> 1) & 3);
      af[f] = *(const f16x8*)&sm[cur][ra * 32 + sa * 8];
    }
#pragma unroll
    for (int f = 0; f < 4; f++) {
      int rb = wn + f * 16 + li, sb = g ^ ((rb >> 1) & 3);
      bf[f] = *(const f16x8*)&sm[cur][2048 + rb * 32 + sb * 8];
    }
#pragma unroll
    for (int mf = 0; mf < 2; mf++)
#pragma unroll
      for (int nf = 0; nf < 4; nf++)
        acc[mf][nf] = MFMA_F16(af[mf], bf[nf], acc[mf][nf]);
    __syncthreads();
  }
#pragma unroll
  for (int mf = 0; mf < 2; mf++)
#pragma unroll
    for (int nf = 0; nf < 4; nf++) {
      int m = mb + wm + mf * 16 + 4 * g;  // 4 consecutive keys in regs 0..3
      int n = nb + wn + nf * 16 + li;     // (h<<8)|c
      f16x4 v = {(f16)acc[mf][nf][0], (f16)acc[mf][nf][1], (f16)acc[mf][nf][2],
                 (f16)acc[mf][nf][3]};
      int bh = (m >> 11) * 8 + (n >> 8);
      size_t o = (size_t)bh * 524288 + (size_t)((m & 2047) >> 5) * 8192 +
                 (size_t)(n & 255) * 32 + (m & 31);
      *(f16x4*)(kvT + o) = v;
    }
}

// --------------------------- flash swishmax attention ------------------------
// grid 512 (16 bh x 32 qb), 4 waves, ONE __syncthreads per tile.
// iter t: barrier -> stage kv(t+1)/K(t+2) -> read kv frags (tile t) ->
//   QK+softmax(t+1) publishing P/sc into parity t+1 -> apply sc(t) ->
//   PV(t) from parity t. PV(t) consumes P published LAST iter, so softmax(t+1)
//   VALU and PV(t) MFMA are independent and interleave.
__global__ __launch_bounds__(256, 2) void flash_attn(const short* __restrict__ q_split,
                                                     const short* __restrict__ k_split,
                                                     const f16* __restrict__ kvT,
                                                     f16* __restrict__ vs_c) {
  __shared__ __attribute__((aligned(16))) short k_lds[2][4096];  // [32k][256B] 2x8KB
  __shared__ __attribute__((aligned(16))) f16 kv_lds[2][8192];   // [256c][64B] 2x16KB
  __shared__ __attribute__((aligned(16))) f16 p_lds[2][4096];    // [64q][128B] 2x8KB
  __shared__ float sc_lds[2][4][16];  // [par][owner wave][q%16] rescale factors
  __shared__ float fix_lds[64];

  const int bid = blockIdx.x;
  const int bh = ((bid & 7) << 1) + ((bid >> 3) & 1);  // 2 bh per XCD for L2 locality
  const int qb = bid >> 4;
  const int tid = threadIdx.x;
  const int w = tid >> 6, lane = tid & 63, g = lane >> 4, li = lane & 15;

  // Q fragments (persist): B-operand, lane holds its q-row's a-slice
  const short* qrow = q_split + ((size_t)bh * 2048 + qb * 64 + w * 16 + li) * 128;
  bf16x8 qf[2][2];
#pragma unroll
  for (int ach = 0; ach < 2; ach++)
#pragma unroll
    for (int hl = 0; hl < 2; hl++)
      qf[ach][hl] = *(const bf16x8*)(qrow + hl * 64 + ach * 32 + g * 8);

  const short* kbase = k_split + (size_t)bh * 262144;
  const f16* kvbase = kvT + (size_t)bh * 524288;

  float m_cur = -INFINITY, m_true = -INFINITY, l_run = 0.f;
  f32x4 acc[4][4] = {};  // [ct][qt]

  auto STAGE_K = [&](int kt, int buf) {
    // K tile [32][256B rows, 16 slots of 16B], read-swz slot^(row&7)
#pragma unroll
    for (int i = 0; i < 2; i++) {
      int off = (w * 2 + i) * 1024 + lane * 16;
      int row = off >> 8;
      int ss = ((off >> 4) & 15) ^ (row & 7);
      g2lds16(kbase + kt * 4096 + row * 128 + ss * 8,
              (char*)k_lds[buf] + (w * 2 + i) * 1024);
    }
  };
  auto STAGE_KV = [&](int kt, int buf) {
    // kv tile [256c][64B rows, 4 slots], read-swz slot^((c>>1)&3); source is
    // the contiguous 16KB k-blocked tile kvT[bh][kt][c][32k]
#pragma unroll
    for (int i = 0; i < 4; i++) {
      int off = (w * 4 + i) * 1024 + lane * 16;
      int c = off >> 6;
      int ss = ((off >> 4) & 3) ^ ((c >> 1) & 3);
      g2lds16(kvbase + kt * 8192 + c * 32 + ss * 8,
              (char*)kv_lds[buf] + (w * 4 + i) * 1024);
    }
  };

  // QK^T + online swishmax for one tile; K from k_lds[buf]; publishes P^T and
  // per-q rescale factor sc into parity buf.
  auto QKSM = [&](int buf) {
    f32x4 s[2] = {};
    __builtin_amdgcn_s_setprio(1);
#pragma unroll
    for (int kc = 0; kc < 2; kc++) {
      const int r = kc * 16 + li;
#pragma unroll
      for (int ach = 0; ach < 2; ach++) {
        int sh = (ach * 4 + g) ^ (r & 7);
        int sl = (8 + ach * 4 + g) ^ (r & 7);
        bf16x8 khi = *(const bf16x8*)((const char*)k_lds[buf] + r * 256 + sh * 16);
        bf16x8 klo = *(const bf16x8*)((const char*)k_lds[buf] + r * 256 + sl * 16);
        s[kc] = MFMA_BF16(khi, qf[ach][0], s[kc]);
        s[kc] = MFMA_BF16(khi, qf[ach][1], s[kc]);
        s[kc] = MFMA_BF16(klo, qf[ach][0], s[kc]);
      }
    }
    __builtin_amdgcn_s_setprio(0);

    // online swishmax; per-lane state is per-q (q = w*16+li after reductions)
    float tmax = fmaxf(fmaxf(fmaxf(s[0][0], s[0][1]), fmaxf(s[0][2], s[0][3])),
                       fmaxf(fmaxf(s[1][0], s[1][1]), fmaxf(s[1][2], s[1][3])));
    tmax = fmaxf(tmax, __shfl_xor(tmax, 16));
    tmax = fmaxf(tmax, __shfl_xor(tmax, 32));
    m_true = fmaxf(m_true, tmax);
    float sc = 1.0f;
    if (__any(tmax > m_cur + 4.0f)) {  // deferred rescale; P <= ~117*e^4 < f16 max
      float mn = fmaxf(m_cur, tmax);
      sc = __expf(m_cur - mn);  // per-q factor (1.0 where tmax <= m_cur)
      l_run *= sc;
      m_cur = mn;
    }
    // publish per-q rescale factor for acc owners (all waves hold acc for q)
    if (g == 0) sc_lds[buf][w][li] = sc;

    float ls = 0.f;
    float pv[8];
#pragma unroll
    for (int kc = 0; kc < 2; kc++)
#pragma unroll
      for (int r2 = 0; r2 < 4; r2++) {
        float sv = s[kc][r2];
        float e = sv * __expf(sv - m_cur);
        pv[kc * 4 + r2] = e;
        ls += fabsf(e);
      }
    ls += __shfl_xor(ls, 16);
    ls += __shfl_xor(ls, 32);
    l_run += ls;

    // write P^T[q][k] (f16) with q-row XOR swizzle ((q&7)<<4 on 128B rows)
#pragma unroll
    for (int kc = 0; kc < 2; kc++) {
      f16x4 p4 = {(f16)pv[kc * 4], (f16)pv[kc * 4 + 1], (f16)pv[kc * 4 + 2],
                  (f16)pv[kc * 4 + 3]};
      int wb = ((w * 16 + li) * 128 + kc * 32 + g * 8) ^ ((li & 7) << 4);
      *(f16x4*)((char*)p_lds[buf] + wb) = p4;
    }
  };

  // prologue: K(0), kv(0), K(1) staged; tile 0's P/sc published into parity 0
  STAGE_K(0, 0);
  STAGE_KV(0, 0);
  STAGE_K(1, 1);
  __syncthreads();
  QKSM(0);

#pragma unroll 2
  for (int kt = 0; kt < 64; kt++) {
    const int cur = kt & 1;
    // P(kt)/sc(kt) visible to all waves; kv(kt)/K(kt+1) stages landed (vmcnt).
    __syncthreads();
    if (kt < 63) STAGE_KV(kt + 1, cur ^ 1);
    if (kt < 62) STAGE_K(kt + 2, cur);

    // kv fragments for PV(kt) — reads parity cur (stages write cur^1 / K cur)
    f16x8 kvf[4];
#pragma unroll
    for (int ct = 0; ct < 4; ct++) {
      int c = w * 64 + ct * 16 + li;
      int ss = g ^ ((c >> 1) & 3);
      kvf[ct] = *(const f16x8*)((const char*)kv_lds[cur] + c * 64 + ss * 16);
    }

    if (kt < 63) QKSM(cur ^ 1);  // tile kt+1 -> parity cur^1

    // apply q-owners' rescale factors for tile kt (rare after warmup)
#pragma unroll
    for (int qt = 0; qt < 4; qt++) {
      float scq = sc_lds[cur][qt][li];
      if (__any(scq != 1.0f)) {
#pragma unroll
        for (int ct = 0; ct < 4; ct++) acc[ct][qt] *= scq;
      }
    }

    // PV(kt): acc[c-quadrant][all q] += kv[c][k] * P^T[k][q]
    __builtin_amdgcn_s_setprio(1);
#pragma unroll
    for (int qt = 0; qt < 4; qt++) {
      int rb = ((qt * 16 + li) * 128 + g * 16) ^ ((li & 7) << 4);
      f16x8 pf = *(const f16x8*)((const char*)p_lds[cur] + rb);
#pragma unroll
      for (int ct = 0; ct < 4; ct++) acc[ct][qt] = MFMA_F16(kvf[ct], pf, acc[ct][qt]);
    }
    __builtin_amdgcn_s_setprio(0);
  }

  // exact fixup to true max (swishmax NOT shift invariant: denom has +1);
  // fixup scalar lives in the q-owner wave -> broadcast via LDS.
  float sfix = __expf(m_cur - m_true);
  float invd = sfix / (l_run * sfix + 1.0f);
  __syncthreads();
  if (g == 0) fix_lds[w * 16 + li] = invd;
  __syncthreads();
#pragma unroll
  for (int qt = 0; qt < 4; qt++) {
    float iv = fix_lds[qt * 16 + li];
    f16* orow = vs_c + ((size_t)(bh >> 3) * 2048 + qb * 64 + qt * 16 + li) * 2048 +
                (bh & 7) * 256 + w * 64 + g * 4;
#pragma unroll
    for (int ct = 0; ct < 4; ct++) {
      f16x4 v = {(f16)(acc[ct][qt][0] * iv), (f16)(acc[ct][qt][1] * iv),
                 (f16)(acc[ct][qt][2] * iv), (f16)(acc[ct][qt][3] * iv)};
      *(f16x4*)(orow + ct * 16) = v;
    }
  }
}

// --------------------------- fp16 final GEMM (head-sum in K) -----------------
// M=4096(b,q) K=2048(h,c) N=1024(t). Tile 64x128. out fp32.
__global__ __launch_bounds__(256, 2) void final_gemm(const f16* __restrict__ A,
                                                     const f16* __restrict__ Bm,
                                                     float* __restrict__ outp) {
  __shared__ __attribute__((aligned(16))) f16 sm[2][6144];  // 24KB dbuf
  int tid = threadIdx.x, w = tid >> 6, lane = tid & 63, g = lane >> 4, li = lane & 15;
  int mb = blockIdx.y * 64, nb = blockIdx.x * 128;
  int wm = (w >> 1) * 32, wn = (w & 1) * 64;
  f32x4 acc[2][4] = {};

  auto STAGE = [&](int kb, int buf) {
    {
      int off = tid * 16;
      int row = off >> 6, ss = ((off >> 4) & 3) ^ ((row >> 1) & 3);
      g2lds16(A + (size_t)(mb + row) * 2048 + kb + ss * 8, (char*)&sm[buf][0] + w * 1024);
    }
#pragma unroll
    for (int i = 0; i < 2; i++) {
      int off = i * 4096 + tid * 16;
      int row = off >> 6, ss = ((off >> 4) & 3) ^ ((row >> 1) & 3);
      g2lds16(Bm + (size_t)(nb + row) * 2048 + kb + ss * 8,
              (char*)&sm[buf][2048] + i * 4096 + w * 1024);
    }
  };

  STAGE(0, 0);
  __syncthreads();
  for (int kb = 0; kb < 2048; kb += 32) {
    int cur = (kb >> 5) & 1;
    if (kb + 32 < 2048) STAGE(kb + 32, cur ^ 1);
    f16x8 af[2], bf[4];
#pragma unroll
    for (int f = 0; f < 2; f++) {
      int ra = wm + f * 16 + li, sa = g ^ ((ra >> 1) & 3);
      af[f] = *(const f16x8*)&sm[cur][ra * 32 + sa * 8];
    }
#pragma unroll
    for (int f = 0; f < 4; f++) {
      int rb = wn + f * 16 + li, sb = g ^ ((rb >> 1) & 3);
      bf[f] = *(const f16x8*)&sm[cur][2048 + rb * 32 + sb * 8];
    }
#pragma unroll
    for (int mf = 0; mf < 2; mf++)
#pragma unroll
      for (int nf = 0; nf < 4; nf++)
        acc[mf][nf] = MFMA_F16(af[mf], bf[nf], acc[mf][nf]);
    __syncthreads();
  }
#pragma unroll
  for (int mf = 0; mf < 2; mf++)
#pragma unroll
    for (int nf = 0; nf < 4; nf++)
#pragma unroll
      for (int r = 0; r < 4; r++) {
        int m = mb + wm + mf * 16 + 4 * g + r;
        int n = nb + wn + nf * 16 + li;
        outp[(size_t)m * 1024 + n] = acc[mf][nf][r];
      }
}

// ---------------------------------------------------------------------------
extern "C" void kernel_launch(void* const* d_in, const int* in_sizes, int n_in,
                              void* d_out, int out_size, void* d_ws, size_t ws_size,
                              hipStream_t stream) {
  (void)in_sizes; (void)n_in; (void)out_size; (void)ws_size;
  const float* qtok = (const float*)d_in[0];  // [2,2048,1024]
  const float* ktok = (const float*)d_in[1];  // [2,2048,1024]
  const float* kdw = (const float*)d_in[2];   // [8,1024,64]
  const float* qdw = (const float*)d_in[3];   // [8,1024,64]
  const float* qdb = (const float*)d_in[4];   // [8,1,64]
  const float* vdw = (const float*)d_in[5];   // [8,1024,256]
  const float* vup = (const float*)d_in[6];   // [8,256,1024]

  char* ws = (char*)d_ws;
  size_t off = 0;
  auto take = [&](size_t n) { void* p = ws + off; off += (n + 255) & ~(size_t)255; return p; };

  short* qtok_hi = (short*)take(8u << 20);  // [4096][1024] bf16
  short* qtok_lo = (short*)take(8u << 20);
  short* ktok_hi = (short*)take(8u << 20);
  short* ktok_lo = (short*)take(8u << 20);
  f16* ktok_f = (f16*)take(8u << 20);       // [4096][1024] f16
  short* wqT_hi = (short*)take(1u << 20);   // [512][1024]
  short* wqT_lo = (short*)take(1u << 20);
  short* wkT_hi = (short*)take(1u << 20);
  short* wkT_lo = (short*)take(1u << 20);
  f16* vdT = (f16*)take(4u << 20);          // [2048][1024] f16 (Wv_down^T)
  f16* vuT = (f16*)take(4u << 20);          // [1024][2048] f16 (Wv_up^T)
  short* q_split = (short*)take(8u << 20);  // [16][2048][128] bf16 hi|lo
  short* k_split = (short*)take(8u << 20);
  // Aliased scratch (stream-ordered safe): {q,k}tok_{hi,lo} dead after proj_gemm.
  f16* kvT = (f16*)(void*)ktok_hi;   // 16MB: [16 bh][64 kt][256 c][32 k]
  f16* vs_c = (f16*)(void*)qtok_hi;  // 16MB: [2][2048][2048]

  ew_split<<<2048, 256, 0, stream>>>(qtok, qtok_hi, qtok_lo, (f16*)nullptr, 1048576);
  ew_split<<<2048, 256, 0, stream>>>(ktok, ktok_hi, ktok_lo, ktok_f, 1048576);
  transpose_split<<<dim3(1, 16, 8), 256, 0, stream>>>(qdw, wqT_hi, wqT_lo, nullptr, 1024, 64);
  transpose_split<<<dim3(1, 16, 8), 256, 0, stream>>>(kdw, wkT_hi, wkT_lo, nullptr, 1024, 64);
  transpose_split<<<dim3(4, 16, 8), 256, 0, stream>>>(vdw, nullptr, nullptr, vdT, 1024, 256);
  transpose_split<<<dim3(16, 32, 1), 256, 0, stream>>>(vup, nullptr, nullptr, vuT, 2048, 1024);

  proj_gemm<<<dim3(4, 64, 2), 256, 0, stream>>>(qtok_hi, qtok_lo, ktok_hi, ktok_lo,
                                                wqT_hi, wqT_lo, wkT_hi, wkT_lo, qdb,
                                                q_split, k_split);
  kv_gemm<<<dim3(16, 64), 256, 0, stream>>>(ktok_f, vdT, kvT);
  flash_attn<<<512, 256, 0, stream>>>(q_split, k_split, kvT, vs_c);
  final_gemm<<<dim3(8, 64), 256, 0, stream>>>(vs_c, vuT, (float*)d_out);
}

// Round 7
// 203.302 us; speedup vs baseline: 1.4007x; 1.1214x over previous
//
#include <hip/hip_runtime.h>
#include <hip/hip_fp16.h>
#include <math.h>

// ---------------------------------------------------------------------------
// AttentionZP: swishmax attention, B=2, H=8, T=1024, A=64, C=256, Q=K=2048.
//
// Round 6 -> 7:
//  * flash_attn: KVBLK=64 (2 kt-tiles per iter) -> barriers 64->32, softmax
//    reductions per key halved, 4 independent QK chains. kv operand moves to
//    wave-private global->reg loads (c-split => no duplication), deleting
//    kv_lds entirely (~35% LDS traffic cut). K stays LDS-staged (shared).
//  * ew_split x2 and transpose_split x4 fused into single dispatches.
// ---------------------------------------------------------------------------

typedef _Float16 f16;
typedef _Float16 f16x4 __attribute__((ext_vector_type(4)));
typedef _Float16 f16x8 __attribute__((ext_vector_type(8)));
typedef short s16x4 __attribute__((ext_vector_type(4)));
typedef short bf16x8 __attribute__((ext_vector_type(8)));
typedef float f32x4 __attribute__((ext_vector_type(4)));

#define MFMA_F16(a, b, c) __builtin_amdgcn_mfma_f32_16x16x32_f16(a, b, c, 0, 0, 0)
#define MFMA_BF16(a, b, c) __builtin_amdgcn_mfma_f32_16x16x32_bf16(a, b, c, 0, 0, 0)

__device__ __forceinline__ void g2lds16(const void* g, void* l) {
  // async global->LDS, 16B/lane; LDS dest is wave-uniform base + lane*16
  __builtin_amdgcn_global_load_lds((__attribute__((address_space(1))) void*)g,
                                   (__attribute__((address_space(3))) void*)l, 16, 0, 0);
}

__device__ __forceinline__ short f32_bf16(float x) {
  union { float f; unsigned u; } v; v.f = x;
  unsigned r = v.u + 0x7FFFu + ((v.u >> 16) & 1u);  // RTN-even
  return (short)(r >> 16);
}
__device__ __forceinline__ float bf16_f32(short h) {
  union { unsigned u; float f; } v; v.u = ((unsigned)(unsigned short)h) << 16;
  return v.f;
}

// --------------------------- prep: elementwise split (both tokens) ----------
__global__ __launch_bounds__(256) void ew_split2(const float* __restrict__ qin,
                                                 const float* __restrict__ kin,
                                                 short* __restrict__ qhi,
                                                 short* __restrict__ qlo,
                                                 short* __restrict__ khi,
                                                 short* __restrict__ klo,
                                                 f16* __restrict__ kf) {
  int i = blockIdx.x * 256 + threadIdx.x;  // 0 .. 2M-1 quads (grid exact)
  const bool isK = i >= 1048576;
  const int j = isK ? i - 1048576 : i;
  const float* in = isK ? kin : qin;
  f32x4 v = ((const f32x4*)in)[j];
  s16x4 h, l;
  f16x4 f;
#pragma unroll
  for (int e = 0; e < 4; e++) {
    short he = f32_bf16(v[e]);
    h[e] = he;
    l[e] = f32_bf16(v[e] - bf16_f32(he));
    f[e] = (f16)v[e];
  }
  if (isK) {
    ((s16x4*)khi)[j] = h;
    ((s16x4*)klo)[j] = l;
    ((f16x4*)kf)[j] = f;
  } else {
    ((s16x4*)qhi)[j] = h;
    ((s16x4*)qlo)[j] = l;
  }
}

// --------------------------- prep: fused transpose (+split) -----------------
// One dispatch for all four weight transposes. Block decode:
//   [0,128)    qdw  [8][1024][64] -> wqT hi/lo  [512][1024]
//   [128,256)  kdw  -> wkT hi/lo
//   [256,768)  vdw  [8][1024][256] -> vdT f16 [2048][1024]
//   [768,1280) vup  [2048][1024]   -> vuT f16 [1024][2048]
__global__ __launch_bounds__(256) void transpose_all(
    const float* __restrict__ qdw, const float* __restrict__ kdw,
    const float* __restrict__ vdw, const float* __restrict__ vup,
    short* __restrict__ wqT_hi, short* __restrict__ wqT_lo,
    short* __restrict__ wkT_hi, short* __restrict__ wkT_lo,
    f16* __restrict__ vdT, f16* __restrict__ vuT) {
  __shared__ float t[64][65];
  int idx = blockIdx.x;
  const float* in;
  short *bhi = nullptr, *blo = nullptr;
  f16* fo = nullptr;
  int R, C, cb, rb;
  size_t batch;
  if (idx < 256) {
    bool isQ = idx < 128;
    int i = isQ ? idx : idx - 128;
    in = isQ ? qdw : kdw;
    bhi = isQ ? wqT_hi : wkT_hi;
    blo = isQ ? wqT_lo : wkT_lo;
    R = 1024; C = 64; cb = 0; rb = (i & 15) * 64;
    batch = (size_t)(i >> 4) * R * C;
  } else if (idx < 768) {
    int i = idx - 256;
    in = vdw; fo = vdT;
    R = 1024; C = 256; cb = (i & 3) * 64; rb = ((i >> 2) & 15) * 64;
    batch = (size_t)(i >> 6) * R * C;
  } else {
    int i = idx - 768;
    in = vup; fo = vuT;
    R = 2048; C = 1024; cb = (i & 15) * 64; rb = (i >> 4) * 64;
    batch = 0;
  }
  int tid = threadIdx.x;
#pragma unroll
  for (int i = 0; i < 4; i++) {
    int r = (tid >> 4) + i * 16, c4 = (tid & 15) * 4;
    f32x4 v = *(const f32x4*)(in + batch + (size_t)(rb + r) * C + cb + c4);
    t[r][c4] = v[0]; t[r][c4 + 1] = v[1]; t[r][c4 + 2] = v[2]; t[r][c4 + 3] = v[3];
  }
  __syncthreads();
#pragma unroll
  for (int i = 0; i < 4; i++) {
    int c = (tid >> 4) + i * 16, r4 = (tid & 15) * 4;
    float v0 = t[r4][c], v1 = t[r4 + 1][c], v2 = t[r4 + 2][c], v3 = t[r4 + 3][c];
    size_t o = batch + (size_t)(cb + c) * R + rb + r4;
    if (bhi) {
      s16x4 h = {f32_bf16(v0), f32_bf16(v1), f32_bf16(v2), f32_bf16(v3)};
      *(s16x4*)(bhi + o) = h;
      s16x4 l = {f32_bf16(v0 - bf16_f32(h[0])), f32_bf16(v1 - bf16_f32(h[1])),
                 f32_bf16(v2 - bf16_f32(h[2])), f32_bf16(v3 - bf16_f32(h[3]))};
      *(s16x4*)(blo + o) = l;
    }
    if (fo) {
      f16x4 fv = {(f16)v0, (f16)v1, (f16)v2, (f16)v3};
      *(f16x4*)(fo + o) = fv;
    }
  }
}

// --------------------------- split-bf16 projection GEMM ----------------------
// M=4096(b,row) K=1024(t) N=512(h,a). Tile 64x128, 4 waves (2x2, 32x64 each).
// out: {q,k}_split[bh][row][ hi(64) | lo(64) ]  (bf16)
__global__ __launch_bounds__(256, 2) void proj_gemm(
    const short* __restrict__ qtok_hi, const short* __restrict__ qtok_lo,
    const short* __restrict__ ktok_hi, const short* __restrict__ ktok_lo,
    const short* __restrict__ wqT_hi, const short* __restrict__ wqT_lo,
    const short* __restrict__ wkT_hi, const short* __restrict__ wkT_lo,
    const float* __restrict__ bias, short* __restrict__ q_split,
    short* __restrict__ k_split) {
  const bool isQ = (blockIdx.z == 0);
  const short* Ahi = isQ ? qtok_hi : ktok_hi;
  const short* Alo = isQ ? qtok_lo : ktok_lo;
  const short* Bhi = isQ ? wqT_hi : wkT_hi;
  const short* Blo = isQ ? wqT_lo : wkT_lo;
  short* outp = isQ ? q_split : k_split;

  // regions (shorts): Ahi[0,2048) Alo[2048,4096) Bhi[4096,8192) Blo[8192,12288)
  __shared__ __attribute__((aligned(16))) short sm[2][12288];  // 48KB dbuf

  int tid = threadIdx.x, w = tid >> 6, lane = tid & 63, g = lane >> 4, li = lane & 15;
  int mb = blockIdx.y * 64, nb = blockIdx.x * 128;
  int wm = (w >> 1) * 32, wn = (w & 1) * 64;

  f32x4 acc[2][4] = {};

  auto STAGE = [&](int kb, int buf) {
    {
      int off = tid * 16;
      int row = off >> 6, ss = ((off >> 4) & 3) ^ ((row >> 1) & 3);
      size_t src = (size_t)(mb + row) * 1024 + kb + ss * 8;
      g2lds16(Ahi + src, (char*)&sm[buf][0] + w * 1024);
      g2lds16(Alo + src, (char*)&sm[buf][2048] + w * 1024);
    }
#pragma unroll
    for (int i = 0; i < 2; i++) {
      int off = i * 4096 + tid * 16;
      int row = off >> 6, ss = ((off >> 4) & 3) ^ ((row >> 1) & 3);
      size_t src = (size_t)(nb + row) * 1024 + kb + ss * 8;
      g2lds16(Bhi + src, (char*)&sm[buf][4096] + i * 4096 + w * 1024);
      g2lds16(Blo + src, (char*)&sm[buf][8192] + i * 4096 + w * 1024);
    }
  };

  STAGE(0, 0);
  __syncthreads();
  for (int kb = 0; kb < 1024; kb += 32) {
    int cur = (kb >> 5) & 1;
    if (kb + 32 < 1024) STAGE(kb + 32, cur ^ 1);
    bf16x8 af[2][2], bf[4][2];
#pragma unroll
    for (int f = 0; f < 2; f++) {
      int ra = wm + f * 16 + li, sa = g ^ ((ra >> 1) & 3);
      af[f][0] = *(const bf16x8*)&sm[cur][ra * 32 + sa * 8];
      af[f][1] = *(const bf16x8*)&sm[cur][2048 + ra * 32 + sa * 8];
    }
#pragma unroll
    for (int f = 0; f < 4; f++) {
      int rb = wn + f * 16 + li, sb = g ^ ((rb >> 1) & 3);
      bf[f][0] = *(const bf16x8*)&sm[cur][4096 + rb * 32 + sb * 8];
      bf[f][1] = *(const bf16x8*)&sm[cur][8192 + rb * 32 + sb * 8];
    }
#pragma unroll
    for (int mf = 0; mf < 2; mf++)
#pragma unroll
      for (int nf = 0; nf < 4; nf++) {
        acc[mf][nf] = MFMA_BF16(af[mf][0], bf[nf][0], acc[mf][nf]);
        acc[mf][nf] = MFMA_BF16(af[mf][0], bf[nf][1], acc[mf][nf]);
        acc[mf][nf] = MFMA_BF16(af[mf][1], bf[nf][0], acc[mf][nf]);
      }
    __syncthreads();
  }
#pragma unroll
  for (int mf = 0; mf < 2; mf++)
#pragma unroll
    for (int nf = 0; nf < 4; nf++)
#pragma unroll
      for (int r = 0; r < 4; r++) {
        int m = mb + wm + mf * 16 + 4 * g + r;
        int n = nb + wn + nf * 16 + li;
        float v = acc[mf][nf][r];
        if (isQ) v += bias[n];
        short hi = f32_bf16(v);
        short lo = f32_bf16(v - bf16_f32(hi));
        size_t base = ((size_t)((m >> 11) * 8 + (n >> 6)) * 2048 + (m & 2047)) * 128;
        outp[base + (n & 63)] = hi;
        outp[base + 64 + (n & 63)] = lo;
      }
}

// --------------------------- fp16 kv GEMM (writes kv k-blocked) -------------
// M=4096(key rows) K=1024(t) N=2048(h,c). Tile 64x128. 4 blocks/CU.
// out kvT[bh][kt=64][c=256][k=32] f16.
__global__ __launch_bounds__(256, 4) void kv_gemm(const f16* __restrict__ A,
                                                  const f16* __restrict__ Bm,
                                                  f16* __restrict__ kvT) {
  __shared__ __attribute__((aligned(16))) f16 sm[2][6144];  // A 2048 + B 4096, 24KB
  int tid = threadIdx.x, w = tid >> 6, lane = tid & 63, g = lane >> 4, li = lane & 15;
  int mb = blockIdx.y * 64, nb = blockIdx.x * 128;
  int wm = (w >> 1) * 32, wn = (w & 1) * 64;
  f32x4 acc[2][4] = {};

  auto STAGE = [&](int kb, int buf) {
    {
      int off = tid * 16;
      int row = off >> 6, ss = ((off >> 4) & 3) ^ ((row >> 1) & 3);
      g2lds16(A + (size_t)(mb + row) * 1024 + kb + ss * 8, (char*)&sm[buf][0] + w * 1024);
    }
#pragma unroll
    for (int i = 0; i < 2; i++) {
      int off = i * 4096 + tid * 16;
      int row = off >> 6, ss = ((off >> 4) & 3) ^ ((row >> 1) & 3);
      g2lds16(Bm + (size_t)(nb + row) * 1024 + kb + ss * 8,
              (char*)&sm[buf][2048] + i * 4096 + w * 1024);
    }
  };

  STAGE(0, 0);
  __syncthreads();
  for (int kb = 0; kb < 1024; kb += 32) {
    int cur = (kb >> 5) & 1;
    if (kb + 32 < 1024) STAGE(kb + 32, cur ^ 1);
    f16x8 af[2], bf[4];
#pragma unroll
    for (int f = 0; f < 2; f++) {
      int ra = wm + f * 16 + li, sa = g ^ ((ra >> 1) & 3);
      af[f] = *(const f16x8*)&sm[cur][ra * 32 + sa * 8];
    }
#pragma unroll
    for (int f = 0; f < 4; f++) {
      int rb = wn + f * 16 + li, sb = g ^ ((rb >> 1) & 3);
      bf[f] = *(const f16x8*)&sm[cur][2048 + rb * 32 + sb * 8];
    }
#pragma unroll
    for (int mf = 0; mf < 2; mf++)
#pragma unroll
      for (int nf = 0; nf < 4; nf++)
        acc[mf][nf] = MFMA_F16(af[mf], bf[nf], acc[mf][nf]);
    __syncthreads();
  }
#pragma unroll
  for (int mf = 0; mf < 2; mf++)
#pragma unroll
    for (int nf = 0; nf < 4; nf++) {
      int m = mb + wm + mf * 16 + 4 * g;  // 4 consecutive keys in regs 0..3
      int n = nb + wn + nf * 16 + li;     // (h<<8)|c
      f16x4 v = {(f16)acc[mf][nf][0], (f16)acc[mf][nf][1], (f16)acc[mf][nf][2],
                 (f16)acc[mf][nf][3]};
      int bh = (m >> 11) * 8 + (n >> 8);
      size_t o = (size_t)bh * 524288 + (size_t)((m & 2047) >> 5) * 8192 +
                 (size_t)(n & 255) * 32 + (m & 31);
      *(f16x4*)(kvT + o) = v;
    }
}

// --------------------------- flash swishmax attention ------------------------
// grid 512 (16 bh x 32 qb), 4 waves, KVBLK=64 keys/iter, 32 iters, ONE barrier
// per iter. K staged to dbuf LDS (shared by all waves); kv loaded global->regs
// (wave-private c-quadrant, zero duplication); P^T + per-q rescale factors via
// dbuf LDS. Skew: iter t runs QK+softmax(t+1) then PV(t).
__global__ __launch_bounds__(256, 2) void flash_attn(const short* __restrict__ q_split,
                                                     const short* __restrict__ k_split,
                                                     const f16* __restrict__ kvT,
                                                     f16* __restrict__ vs_c) {
  __shared__ __attribute__((aligned(16))) short k_lds[2][8192];  // [64k][256B] 2x16KB
  __shared__ __attribute__((aligned(16))) f16 p_lds[2][4096];    // [64q][128B] 2x8KB
  __shared__ float sc_lds[2][4][16];  // [par][owner wave][q%16] rescale factors
  __shared__ float fix_lds[64];

  const int bid = blockIdx.x;
  const int bh = ((bid & 7) << 1) + ((bid >> 3) & 1);  // 2 bh per XCD for L2 locality
  const int qb = bid >> 4;
  const int tid = threadIdx.x;
  const int w = tid >> 6, lane = tid & 63, g = lane >> 4, li = lane & 15;

  // Q fragments (persist): B-operand, lane holds its q-row's a-slice
  const short* qrow = q_split + ((size_t)bh * 2048 + qb * 64 + w * 16 + li) * 128;
  bf16x8 qf[2][2];
#pragma unroll
  for (int ach = 0; ach < 2; ach++)
#pragma unroll
    for (int hl = 0; hl < 2; hl++)
      qf[ach][hl] = *(const bf16x8*)(qrow + hl * 64 + ach * 32 + g * 8);

  const short* kbase = k_split + (size_t)bh * 262144;
  // wave-private kv base: c-quadrant w, A-frag (c row = ct*16+li, k = g*8+j)
  const f16* kvbase = kvT + (size_t)bh * 524288 + (size_t)w * 64 * 32 + li * 32 + g * 8;

  float m_cur = -INFINITY, m_true = -INFINITY, l_run = 0.f;
  f32x4 acc[4][4] = {};  // [ct][qt]
  f16x8 kvf[2][4];       // [k-half][ct] A-frags for this wave's c-quadrant

  auto STAGE_K = [&](int t, int buf) {
    // K tile [64 keys][256B rows, 16 slots of 16B], read-swz slot^(row&7)
#pragma unroll
    for (int i = 0; i < 4; i++) {
      int off = (w * 4 + i) * 1024 + lane * 16;
      int row = off >> 8;
      int ss = ((off >> 4) & 15) ^ (row & 7);
      g2lds16(kbase + t * 8192 + row * 128 + ss * 8,
              (char*)k_lds[buf] + (w * 4 + i) * 1024);
    }
  };

  auto LOADKV = [&](int t) {
    // kvT[bh][kt32][256c][32k]; 64-key tile t = kt32 {2t, 2t+1}
#pragma unroll
    for (int h = 0; h < 2; h++) {
      const f16* p = kvbase + (size_t)(2 * t + h) * 8192;
#pragma unroll
      for (int ct = 0; ct < 4; ct++) kvf[h][ct] = *(const f16x8*)(p + ct * 512);
    }
  };

  // QK^T + online swishmax for 64-key tile; K from k_lds[buf]; publishes P^T
  // and per-q rescale factor sc into parity buf.
  auto QKSM = [&](int buf) {
    f32x4 s[4] = {};
    __builtin_amdgcn_s_setprio(1);
#pragma unroll
    for (int kc = 0; kc < 4; kc++) {
      const int r = kc * 16 + li;
#pragma unroll
      for (int ach = 0; ach < 2; ach++) {
        int sh = (ach * 4 + g) ^ (r & 7);
        int sl = (8 + ach * 4 + g) ^ (r & 7);
        bf16x8 khi = *(const bf16x8*)((const char*)k_lds[buf] + r * 256 + sh * 16);
        bf16x8 klo = *(const bf16x8*)((const char*)k_lds[buf] + r * 256 + sl * 16);
        s[kc] = MFMA_BF16(khi, qf[ach][0], s[kc]);
        s[kc] = MFMA_BF16(khi, qf[ach][1], s[kc]);
        s[kc] = MFMA_BF16(klo, qf[ach][0], s[kc]);
      }
    }
    __builtin_amdgcn_s_setprio(0);

    // online swishmax; per-lane state is per-q (q = w*16+li after reductions)
    float tmax = -INFINITY;
#pragma unroll
    for (int kc = 0; kc < 4; kc++)
      tmax = fmaxf(tmax, fmaxf(fmaxf(s[kc][0], s[kc][1]), fmaxf(s[kc][2], s[kc][3])));
    tmax = fmaxf(tmax, __shfl_xor(tmax, 16));
    tmax = fmaxf(tmax, __shfl_xor(tmax, 32));
    m_true = fmaxf(m_true, tmax);
    float sc = 1.0f;
    if (__any(tmax > m_cur + 4.0f)) {  // deferred rescale; P <= ~117*e^4 < f16 max
      float mn = fmaxf(m_cur, tmax);
      sc = __expf(m_cur - mn);  // per-q factor (1.0 where tmax <= m_cur)
      l_run *= sc;
      m_cur = mn;
    }
    // publish per-q rescale factor for acc owners (all waves hold acc for q)
    if (g == 0) sc_lds[buf][w][li] = sc;

    float ls = 0.f;
    float pv[16];
#pragma unroll
    for (int kc = 0; kc < 4; kc++)
#pragma unroll
      for (int r2 = 0; r2 < 4; r2++) {
        float sv = s[kc][r2];
        float e = sv * __expf(sv - m_cur);
        pv[kc * 4 + r2] = e;
        ls += fabsf(e);
      }
    ls += __shfl_xor(ls, 16);
    ls += __shfl_xor(ls, 32);
    l_run += ls;

    // write P^T[q][64k] (f16), 128B rows, q-row XOR swizzle ((q&7)<<4)
#pragma unroll
    for (int kc = 0; kc < 4; kc++) {
      f16x4 p4 = {(f16)pv[kc * 4], (f16)pv[kc * 4 + 1], (f16)pv[kc * 4 + 2],
                  (f16)pv[kc * 4 + 3]};
      int wb = ((w * 16 + li) * 128 + kc * 32 + g * 8) ^ ((li & 7) << 4);
      *(f16x4*)((char*)p_lds[buf] + wb) = p4;
    }
  };

  // prologue: K(0), K(1) staged; tile 0's P/sc published into parity 0
  STAGE_K(0, 0);
  STAGE_K(1, 1);
  __syncthreads();
  QKSM(0);

#pragma unroll 2
  for (int t = 0; t < 32; t++) {
    const int cur = t & 1;
    // P(t)/sc(t) visible to all waves; K(t+1) stage landed (vmcnt drained).
    __syncthreads();
    LOADKV(t);  // global->reg, wave-private; consumed in PV(t) below
    if (t < 30) STAGE_K(t + 2, cur);
    if (t < 31) QKSM(cur ^ 1);  // tile t+1 -> parity cur^1

    // apply q-owners' rescale factors for tile t (rare after warmup)
#pragma unroll
    for (int qt = 0; qt < 4; qt++) {
      float scq = sc_lds[cur][qt][li];
      if (__any(scq != 1.0f)) {
#pragma unroll
        for (int ct = 0; ct < 4; ct++) acc[ct][qt] *= scq;
      }
    }

    // PV(t): acc[c-quadrant][all q] += kv[c][k] * P^T[k][q]
    __builtin_amdgcn_s_setprio(1);
#pragma unroll
    for (int qt = 0; qt < 4; qt++) {
#pragma unroll
      for (int h = 0; h < 2; h++) {
        int rb = ((qt * 16 + li) * 128 + h * 64 + g * 16) ^ ((li & 7) << 4);
        f16x8 pf = *(const f16x8*)((const char*)p_lds[cur] + rb);
#pragma unroll
        for (int ct = 0; ct < 4; ct++)
          acc[ct][qt] = MFMA_F16(kvf[h][ct], pf, acc[ct][qt]);
      }
    }
    __builtin_amdgcn_s_setprio(0);
  }

  // exact fixup to true max (swishmax NOT shift invariant: denom has +1);
  // fixup scalar lives in the q-owner wave -> broadcast via LDS.
  float sfix = __expf(m_cur - m_true);
  float invd = sfix / (l_run * sfix + 1.0f);
  __syncthreads();
  if (g == 0) fix_lds[w * 16 + li] = invd;
  __syncthreads();
#pragma unroll
  for (int qt = 0; qt < 4; qt++) {
    float iv = fix_lds[qt * 16 + li];
    f16* orow = vs_c + ((size_t)(bh >> 3) * 2048 + qb * 64 + qt * 16 + li) * 2048 +
                (bh & 7) * 256 + w * 64 + g * 4;
#pragma unroll
    for (int ct = 0; ct < 4; ct++) {
      f16x4 v = {(f16)(acc[ct][qt][0] * iv), (f16)(acc[ct][qt][1] * iv),
                 (f16)(acc[ct][qt][2] * iv), (f16)(acc[ct][qt][3] * iv)};
      *(f16x4*)(orow + ct * 16) = v;
    }
  }
}

// --------------------------- fp16 final GEMM (head-sum in K) -----------------
// M=4096(b,q) K=2048(h,c) N=1024(t). Tile 64x128. out fp32.
__global__ __launch_bounds__(256, 2) void final_gemm(const f16* __restrict__ A,
                                                     const f16* __restrict__ Bm,
                                                     float* __restrict__ outp) {
  __shared__ __attribute__((aligned(16))) f16 sm[2][6144];  // 24KB dbuf
  int tid = threadIdx.x, w = tid >> 6, lane = tid & 63, g = lane >> 4, li = lane & 15;
  int mb = blockIdx.y * 64, nb = blockIdx.x * 128;
  int wm = (w >> 1) * 32, wn = (w & 1) * 64;
  f32x4 acc[2][4] = {};

  auto STAGE = [&](int kb, int buf) {
    {
      int off = tid * 16;
      int row = off >> 6, ss = ((off >> 4) & 3) ^ ((row >> 1) & 3);
      g2lds16(A + (size_t)(mb + row) * 2048 + kb + ss * 8, (char*)&sm[buf][0] + w * 1024);
    }
#pragma unroll
    for (int i = 0; i < 2; i++) {
      int off = i * 4096 + tid * 16;
      int row = off >> 6, ss = ((off >> 4) & 3) ^ ((row >> 1) & 3);
      g2lds16(Bm + (size_t)(nb + row) * 2048 + kb + ss * 8,
              (char*)&sm[buf][2048] + i * 4096 + w * 1024);
    }
  };

  STAGE(0, 0);
  __syncthreads();
  for (int kb = 0; kb < 2048; kb += 32) {
    int cur = (kb >> 5) & 1;
    if (kb + 32 < 2048) STAGE(kb + 32, cur ^ 1);
    f16x8 af[2], bf[4];
#pragma unroll
    for (int f = 0; f < 2; f++) {
      int ra = wm + f * 16 + li, sa = g ^ ((ra >> 1) & 3);
      af[f] = *(const f16x8*)&sm[cur][ra * 32 + sa * 8];
    }
#pragma unroll
    for (int f = 0; f < 4; f++) {
      int rb = wn + f * 16 + li, sb = g ^ ((rb >> 1) & 3);
      bf[f] = *(const f16x8*)&sm[cur][2048 + rb * 32 + sb * 8];
    }
#pragma unroll
    for (int mf = 0; mf < 2; mf++)
#pragma unroll
      for (int nf = 0; nf < 4; nf++)
        acc[mf][nf] = MFMA_F16(af[mf], bf[nf], acc[mf][nf]);
    __syncthreads();
  }
#pragma unroll
  for (int mf = 0; mf < 2; mf++)
#pragma unroll
    for (int nf = 0; nf < 4; nf++)
#pragma unroll
      for (int r = 0; r < 4; r++) {
        int m = mb + wm + mf * 16 + 4 * g + r;
        int n = nb + wn + nf * 16 + li;
        outp[(size_t)m * 1024 + n] = acc[mf][nf][r];
      }
}

// ---------------------------------------------------------------------------
extern "C" void kernel_launch(void* const* d_in, const int* in_sizes, int n_in,
                              void* d_out, int out_size, void* d_ws, size_t ws_size,
                              hipStream_t stream) {
  (void)in_sizes; (void)n_in; (void)out_size; (void)ws_size;
  const float* qtok = (const float*)d_in[0];  // [2,2048,1024]
  const float* ktok = (const float*)d_in[1];  // [2,2048,1024]
  const float* kdw = (const float*)d_in[2];   // [8,1024,64]
  const float* qdw = (const float*)d_in[3];   // [8,1024,64]
  const float* qdb = (const float*)d_in[4];   // [8,1,64]
  const float* vdw = (const float*)d_in[5];   // [8,1024,256]
  const float* vup = (const float*)d_in[6];   // [8,256,1024]

  char* ws = (char*)d_ws;
  size_t off = 0;
  auto take = [&](size_t n) { void* p = ws + off; off += (n + 255) & ~(size_t)255; return p; };

  short* qtok_hi = (short*)take(8u << 20);  // [4096][1024] bf16
  short* qtok_lo = (short*)take(8u << 20);
  short* ktok_hi = (short*)take(8u << 20);
  short* ktok_lo = (short*)take(8u << 20);
  f16* ktok_f = (f16*)take(8u << 20);       // [4096][1024] f16
  short* wqT_hi = (short*)take(1u << 20);   // [512][1024]
  short* wqT_lo = (short*)take(1u << 20);
  short* wkT_hi = (short*)take(1u << 20);
  short* wkT_lo = (short*)take(1u << 20);
  f16* vdT = (f16*)take(4u << 20);          // [2048][1024] f16 (Wv_down^T)
  f16* vuT = (f16*)take(4u << 20);          // [1024][2048] f16 (Wv_up^T)
  short* q_split = (short*)take(8u << 20);  // [16][2048][128] bf16 hi|lo
  short* k_split = (short*)take(8u << 20);
  // Aliased scratch (stream-ordered safe): {q,k}tok_{hi,lo} dead after proj_gemm.
  f16* kvT = (f16*)(void*)ktok_hi;   // 16MB: [16 bh][64 kt][256 c][32 k]
  f16* vs_c = (f16*)(void*)qtok_hi;  // 16MB: [2][2048][2048]

  ew_split2<<<8192, 256, 0, stream>>>(qtok, ktok, qtok_hi, qtok_lo, ktok_hi,
                                      ktok_lo, ktok_f);
  transpose_all<<<1280, 256, 0, stream>>>(qdw, kdw, vdw, vup, wqT_hi, wqT_lo,
                                          wkT_hi, wkT_lo, vdT, vuT);
  proj_gemm<<<dim3(4, 64, 2), 256, 0, stream>>>(qtok_hi, qtok_lo, ktok_hi, ktok_lo,
                                                wqT_hi, wqT_lo, wkT_hi, wkT_lo, qdb,
                                                q_split, k_split);
  kv_gemm<<<dim3(16, 64), 256, 0, stream>>>(ktok_f, vdT, kvT);
  flash_attn<<<512, 256, 0, stream>>>(q_split, k_split, kvT, vs_c);
  final_gemm<<<dim3(8, 64), 256, 0, stream>>>(vs_c, vuT, (float*)d_out);
}